// Round 3
// baseline (1681.504 us; speedup 1.0000x reference)
//
#include <hip/hip_runtime.h>
#include <math.h>

#define NND 65536   // total nodes
#define NPER 512    // nodes per graph
#define NGR 128     // graphs (B)
#define DD 128      // feature dim
#define NED 524288  // edges

// ---------------- CSR build ----------------

__global__ __launch_bounds__(256) void init_kernel(int* __restrict__ counts,
                                                   int* __restrict__ mask) {
  int i = blockIdx.x * 256 + threadIdx.x;
  counts[i] = 0;
  mask[i] = 1;
}

__global__ __launch_bounds__(256) void hist_kernel(const int* __restrict__ ei,
                                                   int* __restrict__ counts) {
  int e = blockIdx.x * 256 + threadIdx.x;
  atomicAdd(&counts[ei[NED + e]], 1);
}

__global__ __launch_bounds__(1024) void scan_kernel(const int* __restrict__ counts,
                                                    int* __restrict__ off,
                                                    int* __restrict__ cursor) {
  __shared__ int part[1024];
  int t = threadIdx.x;
  int base = t * 64;
  int s = 0;
  for (int i = 0; i < 64; ++i) s += counts[base + i];
  part[t] = s;
  __syncthreads();
  for (int d = 1; d < 1024; d <<= 1) {
    int v = (t >= d) ? part[t - d] : 0;
    __syncthreads();
    part[t] += v;
    __syncthreads();
  }
  int run = (t == 0) ? 0 : part[t - 1];
  for (int i = 0; i < 64; ++i) {
    off[base + i] = run;
    cursor[base + i] = run;
    run += counts[base + i];
  }
  if (t == 1023) off[NND] = run;
}

__global__ __launch_bounds__(256) void scatter_kernel(const int* __restrict__ ei,
                                                      int* __restrict__ cursor,
                                                      int* __restrict__ ssrc) {
  int e = blockIdx.x * 256 + threadIdx.x;
  int dst = ei[NED + e];
  int pos = atomicAdd(&cursor[dst], 1);
  ssrc[pos] = ei[e];
}

// ---------------- weight transpose (wT[k][f] = w[f][k]) ----------------

__global__ __launch_bounds__(256) void transpose6_kernel(
    const float* __restrict__ w0, const float* __restrict__ w1,
    const float* __restrict__ w2, const float* __restrict__ w3,
    const float* __restrict__ w4, const float* __restrict__ w5,
    float* __restrict__ out) {
  const float* srcs[6] = {w0, w1, w2, w3, w4, w5};
  const float* s = srcs[blockIdx.x];
  float* d = out + (size_t)blockIdx.x * DD * DD;
  for (int i = threadIdx.x; i < DD * DD; i += 256) {
    int f = i >> 7, k = i & 127;
    d[k * DD + f] = s[i];
  }
}

// ---------------- mask-gated mean aggregation ----------------
// One wave per dst; 64-edge index batches broadcast via shfl; two 32-lane
// halves gather different edges as float4. Dead src rows are ZERO (pool
// zeroes them) so no mask guard on the sum; deg via ballot. XCD swizzle
// keeps one graph's x-slice in one XCD's L2.

template <int CM>
__global__ __launch_bounds__(256) void agg_kernel_t(const float* __restrict__ x,
                                                    const int* __restrict__ mask,
                                                    const int* __restrict__ off,
                                                    const int* __restrict__ ssrc,
                                                    float* __restrict__ mean) {
  const int wave = threadIdx.x >> 6;
  const int lane = threadIdx.x & 63;
  const int half = lane >> 5;
  const int l = lane & 31;
  const int bid = blockIdx.x;
  const int xcd = bid & 7;
  const int slot = bid >> 3;
  const int graph = xcd * 16 + (slot >> 7);
  const int within = slot & 127;
  const int dst = graph * NPER + within * 4 + wave;

  if (CM && !mask[dst]) {
    if (lane < 32) *(float4*)(mean + (size_t)dst * DD + l * 4) = make_float4(0.f, 0.f, 0.f, 0.f);
    return;
  }
  const int beg = off[dst], end = off[dst + 1];
  float4 acc = make_float4(0.f, 0.f, 0.f, 0.f);
  int deg = 0;
  for (int base = beg; base < end; base += 64) {
    const int n = min(64, end - base);
    int sv = 0, mv = 0;
    if (lane < n) {
      sv = ssrc[base + lane];
      if (CM) mv = mask[sv];
    }
    if (CM)
      deg += (int)__popcll(__ballot(mv != 0));
    else
      deg += n;
    for (int j = half; j < n; j += 2) {
      const int s = __shfl(sv, j);
      const float4 v = *(const float4*)(x + (size_t)s * DD + l * 4);
      acc.x += v.x;
      acc.y += v.y;
      acc.z += v.z;
      acc.w += v.w;
    }
  }
  acc.x += __shfl(acc.x, lane ^ 32);
  acc.y += __shfl(acc.y, lane ^ 32);
  acc.z += __shfl(acc.z, lane ^ 32);
  acc.w += __shfl(acc.w, lane ^ 32);
  const float inv = 1.f / (float)max(deg, 1);
  if (lane < 32) {
    float4 m;
    m.x = acc.x * inv;
    m.y = acc.y * inv;
    m.z = acc.z * inv;
    m.w = acc.w * inv;
    *(float4*)(mean + (size_t)dst * DD + l * 4) = m;
  }
}

// ---------------- fused SAGE GEMM: relu([mean|x] @ [wlT;wrT] + bl) ----------------
// BM=64, BN=128, BK=32, 256 threads, 4x8 microtile, register prefetch of the
// next K-chunk so staging latency overlaps compute. Wave-level 8x8 lane grid
// (tr/tc contiguous per wave) -> As/Bs reads are <=2-way conflicts (free).
// As transposed [k][row] stride 65 -> store conflicts <=2-way (free).

#define GBM 64
#define GBK 32
#define ASTR 65

__global__ __launch_bounds__(256, 4) void gemm_kernel(const float* __restrict__ Amean,
                                                      const float* __restrict__ Ax,
                                                      const float* __restrict__ wlT,
                                                      const float* __restrict__ wrT,
                                                      const float* __restrict__ bias,
                                                      float* __restrict__ outp) {
  __shared__ float As[GBK * ASTR];
  __shared__ float Bs[GBK * DD];
  const int tid = threadIdx.x;
  const int wv = tid >> 6;
  const int lane = tid & 63;
  const int tr = ((wv >> 1) << 3) + (lane >> 3);  // 0..15, 4 rows each
  const int tc = ((wv & 1) << 3) + (lane & 7);    // 0..15, 8 cols each
  const int row0 = blockIdx.x * GBM;

  float acc[4][8];
#pragma unroll
  for (int i = 0; i < 4; ++i)
#pragma unroll
    for (int j = 0; j < 8; ++j) acc[i][j] = 0.f;

  float4 pa[2], pb[4];

#define LOAD_AB(KC)                                                                        \
  {                                                                                        \
    const float* Asrc = ((KC) < 4) ? Amean : Ax;                                           \
    const int ab = ((KC) & 3) * GBK;                                                       \
    _Pragma("unroll") for (int i = 0; i < 2; ++i) {                                        \
      const int id = tid + i * 256;                                                        \
      pa[i] = *(const float4*)(Asrc + (size_t)(row0 + (id >> 3)) * DD + ab + ((id & 7) << 2)); \
    }                                                                                      \
    _Pragma("unroll") for (int i = 0; i < 4; ++i) {                                        \
      const int id = tid + i * 256;                                                        \
      const int gk = (KC)*GBK + (id >> 5);                                                 \
      const float* Bsrc = (gk < DD) ? (wlT + (size_t)gk * DD) : (wrT + (size_t)(gk - DD) * DD); \
      pb[i] = *(const float4*)(Bsrc + ((id & 31) << 2));                                   \
    }                                                                                      \
  }

  LOAD_AB(0)

#pragma unroll
  for (int kc = 0; kc < 8; ++kc) {
// store staged regs to LDS
#pragma unroll
    for (int i = 0; i < 2; ++i) {
      const int id = tid + i * 256;
      const int r = id >> 3;
      const int kk = (id & 7) << 2;
      As[(kk + 0) * ASTR + r] = pa[i].x;
      As[(kk + 1) * ASTR + r] = pa[i].y;
      As[(kk + 2) * ASTR + r] = pa[i].z;
      As[(kk + 3) * ASTR + r] = pa[i].w;
    }
#pragma unroll
    for (int i = 0; i < 4; ++i) {
      const int id = tid + i * 256;
      *(float4*)(Bs + (id >> 5) * DD + ((id & 31) << 2)) = pb[i];
    }
    __syncthreads();
    if (kc < 7) LOAD_AB(kc + 1)  // overlaps with compute below
#pragma unroll
    for (int k = 0; k < GBK; ++k) {
      const float4 a0 = *(const float4*)(As + k * ASTR + tr * 4);
      const float4 b0 = *(const float4*)(Bs + k * DD + tc * 8);
      const float4 b1 = *(const float4*)(Bs + k * DD + tc * 8 + 4);
      const float av[4] = {a0.x, a0.y, a0.z, a0.w};
      const float bv[8] = {b0.x, b0.y, b0.z, b0.w, b1.x, b1.y, b1.z, b1.w};
#pragma unroll
      for (int i2 = 0; i2 < 4; ++i2)
#pragma unroll
        for (int j2 = 0; j2 < 8; ++j2) acc[i2][j2] = fmaf(av[i2], bv[j2], acc[i2][j2]);
    }
    __syncthreads();
  }
#undef LOAD_AB

  const int c0 = tc * 8;
  const float4 bb0 = *(const float4*)(bias + c0);
  const float4 bb1 = *(const float4*)(bias + c0 + 4);
#pragma unroll
  for (int i = 0; i < 4; ++i) {
    const int r = row0 + tr * 4 + i;
    float4 o0, o1;
    o0.x = fmaxf(acc[i][0] + bb0.x, 0.f);
    o0.y = fmaxf(acc[i][1] + bb0.y, 0.f);
    o0.z = fmaxf(acc[i][2] + bb0.z, 0.f);
    o0.w = fmaxf(acc[i][3] + bb0.w, 0.f);
    o1.x = fmaxf(acc[i][4] + bb1.x, 0.f);
    o1.y = fmaxf(acc[i][5] + bb1.y, 0.f);
    o1.z = fmaxf(acc[i][6] + bb1.z, 0.f);
    o1.w = fmaxf(acc[i][7] + bb1.w, 0.f);
    *(float4*)(outp + (size_t)r * DD + c0) = o0;
    *(float4*)(outp + (size_t)r * DD + c0 + 4) = o1;
  }
}

// ---------------- topk: score + exact rank + mask/tanh table ----------------
// one block per graph, 512 threads; thread n = node n.

__global__ __launch_bounds__(512) void topk_kernel(const float* __restrict__ h,
                                                   const float* __restrict__ pw,
                                                   int* __restrict__ mask,
                                                   float* __restrict__ tbuf,
                                                   const int kk) {
  __shared__ float s_sc[NPER];
  __shared__ float s_norm;
  const int g = blockIdx.x;
  const int tid = threadIdx.x;
  const int lane = tid & 63;

  if (tid < 64) {
    const float v0 = pw[lane], v1 = pw[lane + 64];
    float p = v0 * v0 + v1 * v1;
#pragma unroll
    for (int o = 32; o > 0; o >>= 1) p += __shfl_down(p, o);
    if (lane == 0) s_norm = 1.f / (sqrtf(p) + 1e-16f);
  }

  // dot product: thread n over its own row
  const int node = g * NPER + tid;
  const float4* hp = (const float4*)(h + (size_t)node * DD);
  const float4* pw4 = (const float4*)pw;
  float ax = 0.f, ay = 0.f, az = 0.f, aw = 0.f;
#pragma unroll
  for (int i = 0; i < 32; ++i) {
    const float4 xv = hp[i];
    const float4 wv = pw4[i];
    ax = fmaf(xv.x, wv.x, ax);
    ay = fmaf(xv.y, wv.y, ay);
    az = fmaf(xv.z, wv.z, az);
    aw = fmaf(xv.w, wv.w, aw);
  }
  const float sc = (ax + ay) + (az + aw);
  __syncthreads();
  s_sc[tid] = mask[node] ? sc * s_norm : -INFINITY;
  __syncthreads();

  // exact top-k via rank counting (stable tie-break by index = lax.top_k)
  const float s = s_sc[tid];
  int rank = 0;
  for (int j = 0; j < NPER; ++j) {
    const float sj = s_sc[j];
    rank += (sj > s || (sj == s && j < tid)) ? 1 : 0;
  }
  const int sel = (rank < kk) ? 1 : 0;
  mask[node] = sel;
  tbuf[node] = sel ? tanhf(s) : 0.f;
}

// ---------------- scale + partial readout ----------------
// 256 blocks = 2 per graph (256 nodes each), 256 threads. Zeroes unselected
// rows (t=0), tanh-scales selected, partial max/sum -> zpart[l][block][256].

__global__ __launch_bounds__(256) void scale_readout_kernel(float* __restrict__ h,
                                                            const float* __restrict__ tbuf,
                                                            const int* __restrict__ mask,
                                                            float* __restrict__ zp) {
  __shared__ float red[4 * 128];
  const int b = blockIdx.x;
  const int g = b >> 1;
  const int q = b & 1;
  const int tid = threadIdx.x;
  const int fcol = tid & 127;
  const int off = tid >> 7;  // 0..1
  float pmax = -INFINITY;
  float psum = 0.f;
  const int nbase = g * NPER + q * 256;
  for (int i = 0; i < 128; ++i) {
    const int n = nbase + off + 2 * i;
    float* hp = h + (size_t)n * DD + fcol;
    const float t = tbuf[n];  // 0 for unselected
    const float v = *hp * t;
    *hp = v;
    psum += v;
    if (mask[n]) pmax = fmaxf(pmax, v);
  }
  red[off * 128 + fcol] = pmax;
  red[256 + off * 128 + fcol] = psum;
  __syncthreads();
  if (tid < 128) {
    float* row = zp + (size_t)b * 256;
    row[tid] = fmaxf(red[tid], red[128 + tid]);
    row[128 + tid] = red[256 + tid] + red[384 + tid];
  }
}

// ---------------- MLP head (reduces zpart partials) ----------------

__global__ __launch_bounds__(128) void mlp_kernel(const float* __restrict__ zpart,
                                                  const float* __restrict__ w1,
                                                  const float* __restrict__ b1,
                                                  const float* __restrict__ w2,
                                                  const float* __restrict__ b2,
                                                  const float* __restrict__ w3,
                                                  const float* __restrict__ b3,
                                                  float* __restrict__ out,
                                                  const float ik0, const float ik1,
                                                  const float ik2) {
  __shared__ float z[256];
  __shared__ float h1[128];
  __shared__ float h2[64];
  const int g = blockIdx.x;
  const int t = threadIdx.x;
  const float iks[3] = {ik0, ik1, ik2};
  float zmax = 0.f, zmean = 0.f;
#pragma unroll
  for (int l = 0; l < 3; ++l) {
    const float* zp = zpart + ((size_t)l * 256 + g * 2) * 256;
    zmax += fmaxf(zp[t], zp[256 + t]);
    zmean += (zp[128 + t] + zp[384 + t]) * iks[l];
  }
  z[t] = zmax;
  z[128 + t] = zmean;
  __syncthreads();
  float a = b1[t];
  for (int k = 0; k < 256; ++k) a = fmaf(z[k], w1[t * 256 + k], a);
  h1[t] = fmaxf(a, 0.f);
  __syncthreads();
  if (t < 64) {
    float a2 = b2[t];
    for (int k = 0; k < 128; ++k) a2 = fmaf(h1[k], w2[t * 128 + k], a2);
    h2[t] = fmaxf(a2, 0.f);
  }
  __syncthreads();
  if (t == 0) {
    float a3 = b3[0];
    for (int k = 0; k < 64; ++k) a3 = fmaf(h2[k], w3[k], a3);
    out[g] = 1.f / (1.f + expf(-a3));
  }
}

// ---------------- launch ----------------

extern "C" void kernel_launch(void* const* d_in, const int* in_sizes, int n_in,
                              void* d_out, int out_size, void* d_ws, size_t ws_size,
                              hipStream_t stream) {
  (void)in_sizes; (void)n_in; (void)out_size; (void)ws_size;
  const float* x_in = (const float*)d_in[0];
  const int* ei = (const int*)d_in[1];
  const float* wl[3] = {(const float*)d_in[2], (const float*)d_in[6], (const float*)d_in[10]};
  const float* cbl[3] = {(const float*)d_in[3], (const float*)d_in[7], (const float*)d_in[11]};
  const float* wr[3] = {(const float*)d_in[4], (const float*)d_in[8], (const float*)d_in[12]};
  const float* pw[3] = {(const float*)d_in[5], (const float*)d_in[9], (const float*)d_in[13]};
  const float* l1w = (const float*)d_in[14];
  const float* l1b = (const float*)d_in[15];
  const float* l2w = (const float*)d_in[16];
  const float* l2b = (const float*)d_in[17];
  const float* l3w = (const float*)d_in[18];
  const float* l3b = (const float*)d_in[19];
  float* out = (float*)d_out;

  char* w = (char*)d_ws;
  int* counts = (int*)(w + 0 * (1 << 20));   // dead after setup
  float* tbuf = (float*)(w + 0 * (1 << 20)); // reuses counts region (256KB)
  int* off = (int*)(w + 1 * (1 << 20));
  int* cursor = (int*)(w + 2 * (1 << 20));
  int* mask = (int*)(w + 3 * (1 << 20));
  float* zpart = (float*)(w + 4 * (1 << 20));  // 3*256*256 floats = 768KB
  float* wT = (float*)(w + 5 * (1 << 20));     // 6 * 64KB
  int* ssrc = (int*)(w + 6 * (1 << 20));       // 2MB
  float* mean = (float*)(w + (size_t)8 * (1 << 20));   // 32MB
  float* hA = (float*)(w + (size_t)40 * (1 << 20));    // 32MB
  float* hB = (float*)(w + (size_t)72 * (1 << 20));    // 32MB (total 104MB)

  // NOTE: tbuf overlaps counts -- counts only used by init/hist/scan (setup),
  // tbuf only written after setup completes. Same-stream ordering guarantees it.

  init_kernel<<<NND / 256, 256, 0, stream>>>(counts, mask);
  hist_kernel<<<NED / 256, 256, 0, stream>>>(ei, counts);
  scan_kernel<<<1, 1024, 0, stream>>>(counts, off, cursor);
  scatter_kernel<<<NED / 256, 256, 0, stream>>>(ei, cursor, ssrc);
  transpose6_kernel<<<6, 256, 0, stream>>>(wl[0], wr[0], wl[1], wr[1], wl[2], wr[2], wT);

  const int ks[3] = {410, 328, 263};
  const float* xl = x_in;
  float* houts[3] = {hA, hB, hA};
  for (int l = 0; l < 3; ++l) {
    float* hout = houts[l];
    if (l == 0)
      agg_kernel_t<0><<<NND / 4, 256, 0, stream>>>(xl, mask, off, ssrc, mean);
    else
      agg_kernel_t<1><<<NND / 4, 256, 0, stream>>>(xl, mask, off, ssrc, mean);
    gemm_kernel<<<NND / GBM, 256, 0, stream>>>(mean, xl, wT + (size_t)(2 * l) * DD * DD,
                                               wT + (size_t)(2 * l + 1) * DD * DD, cbl[l], hout);
    topk_kernel<<<NGR, 512, 0, stream>>>(hout, pw[l], mask, tbuf, ks[l]);
    scale_readout_kernel<<<NGR * 2, 256, 0, stream>>>(hout, tbuf, mask,
                                                      zpart + (size_t)l * 256 * 256);
    xl = hout;
  }
  mlp_kernel<<<NGR, 128, 0, stream>>>(zpart, l1w, l1b, l2w, l2b, l3w, l3b, out,
                                      1.f / 410.f, 1.f / 328.f, 1.f / 263.f);
}

// Round 4
// 608.203 us; speedup vs baseline: 2.7647x; 2.7647x over previous
//
#include <hip/hip_runtime.h>
#include <math.h>

#define NND 65536   // total nodes
#define NPER 512    // nodes per graph
#define NGR 128     // graphs (B)
#define DD 128      // feature dim
#define NED 524288  // edges

// ---------------- CSR build ----------------

__global__ __launch_bounds__(256) void init_kernel(int* __restrict__ counts,
                                                   int* __restrict__ mask) {
  int i = blockIdx.x * 256 + threadIdx.x;
  counts[i] = 0;
  mask[i] = 1;
}

__global__ __launch_bounds__(256) void hist_kernel(const int* __restrict__ ei,
                                                   int* __restrict__ counts) {
  int e = blockIdx.x * 256 + threadIdx.x;
  atomicAdd(&counts[ei[NED + e]], 1);
}

__global__ __launch_bounds__(1024) void scan_kernel(const int* __restrict__ counts,
                                                    int* __restrict__ off,
                                                    int* __restrict__ cursor) {
  __shared__ int part[1024];
  int t = threadIdx.x;
  int base = t * 64;
  int s = 0;
  for (int i = 0; i < 64; ++i) s += counts[base + i];
  part[t] = s;
  __syncthreads();
  for (int d = 1; d < 1024; d <<= 1) {
    int v = (t >= d) ? part[t - d] : 0;
    __syncthreads();
    part[t] += v;
    __syncthreads();
  }
  int run = (t == 0) ? 0 : part[t - 1];
  for (int i = 0; i < 64; ++i) {
    off[base + i] = run;
    cursor[base + i] = run;
    run += counts[base + i];
  }
  if (t == 1023) off[NND] = run;
}

__global__ __launch_bounds__(256) void scatter_kernel(const int* __restrict__ ei,
                                                      int* __restrict__ cursor,
                                                      int* __restrict__ ssrc) {
  int e = blockIdx.x * 256 + threadIdx.x;
  int dst = ei[NED + e];
  int pos = atomicAdd(&cursor[dst], 1);
  ssrc[pos] = ei[e];
}

// ---------------- weight transpose (wT[k][f] = w[f][k]) ----------------

__global__ __launch_bounds__(256) void transpose6_kernel(
    const float* __restrict__ w0, const float* __restrict__ w1,
    const float* __restrict__ w2, const float* __restrict__ w3,
    const float* __restrict__ w4, const float* __restrict__ w5,
    float* __restrict__ out) {
  const float* srcs[6] = {w0, w1, w2, w3, w4, w5};
  const float* s = srcs[blockIdx.x];
  float* d = out + (size_t)blockIdx.x * DD * DD;
  for (int i = threadIdx.x; i < DD * DD; i += 256) {
    int f = i >> 7, k = i & 127;
    d[k * DD + f] = s[i];
  }
}

// ---------------- mask-gated mean aggregation ----------------
// One wave per dst; 64-edge index batches broadcast via shfl; two 32-lane
// halves gather different edges as float4. Dead src rows are ZERO so no mask
// guard on the sum; deg via ballot. XCD swizzle keeps a graph's x-slice in
// one XCD's L2.

template <int CM>
__global__ __launch_bounds__(256) void agg_kernel_t(const float* __restrict__ x,
                                                    const int* __restrict__ mask,
                                                    const int* __restrict__ off,
                                                    const int* __restrict__ ssrc,
                                                    float* __restrict__ mean) {
  const int wave = threadIdx.x >> 6;
  const int lane = threadIdx.x & 63;
  const int half = lane >> 5;
  const int l = lane & 31;
  const int bid = blockIdx.x;
  const int xcd = bid & 7;
  const int slot = bid >> 3;
  const int graph = xcd * 16 + (slot >> 7);
  const int within = slot & 127;
  const int dst = graph * NPER + within * 4 + wave;

  if (CM && !mask[dst]) {
    if (lane < 32) *(float4*)(mean + (size_t)dst * DD + l * 4) = make_float4(0.f, 0.f, 0.f, 0.f);
    return;
  }
  const int beg = off[dst], end = off[dst + 1];
  float4 acc = make_float4(0.f, 0.f, 0.f, 0.f);
  int deg = 0;
  for (int base = beg; base < end; base += 64) {
    const int n = min(64, end - base);
    int sv = 0, mv = 0;
    if (lane < n) {
      sv = ssrc[base + lane];
      if (CM) mv = mask[sv];
    }
    if (CM)
      deg += (int)__popcll(__ballot(mv != 0));
    else
      deg += n;
    for (int j = half; j < n; j += 2) {
      const int s = __shfl(sv, j);
      const float4 v = *(const float4*)(x + (size_t)s * DD + l * 4);
      acc.x += v.x;
      acc.y += v.y;
      acc.z += v.z;
      acc.w += v.w;
    }
  }
  acc.x += __shfl(acc.x, lane ^ 32);
  acc.y += __shfl(acc.y, lane ^ 32);
  acc.z += __shfl(acc.z, lane ^ 32);
  acc.w += __shfl(acc.w, lane ^ 32);
  const float inv = 1.f / (float)max(deg, 1);
  if (lane < 32) {
    float4 m;
    m.x = acc.x * inv;
    m.y = acc.y * inv;
    m.z = acc.z * inv;
    m.w = acc.w * inv;
    *(float4*)(mean + (size_t)dst * DD + l * 4) = m;
  }
}

// ---------------- fused SAGE GEMM + score epilogue ----------------
// h = relu([mean|x] @ [wlT;wrT] + bl); sraw[node] = h[node] . pw
// BM=64, BK=32, 256 threads, 4x8 microtile, register prefetch.
// NO min-occupancy launch bound (R3: forcing 4 waves/EU capped VGPR at 64 ->
// 900MB scratch spill). Wave-level 8x8 lane grid -> LDS conflicts = 0
// (measured R2). As transposed [k][row] stride 65.

#define GBM 64
#define GBK 32
#define ASTR 65

__global__ __launch_bounds__(256) void gemm_kernel(const float* __restrict__ Amean,
                                                   const float* __restrict__ Ax,
                                                   const float* __restrict__ wlT,
                                                   const float* __restrict__ wrT,
                                                   const float* __restrict__ bias,
                                                   const float* __restrict__ pw,
                                                   float* __restrict__ outp,
                                                   float* __restrict__ sraw) {
  __shared__ float As[GBK * ASTR];
  __shared__ float Bs[GBK * DD];
  __shared__ float s_part[64 * 17];
  const int tid = threadIdx.x;
  const int wv = tid >> 6;
  const int lane = tid & 63;
  const int tr = ((wv >> 1) << 3) + (lane >> 3);  // 0..15, 4 rows each
  const int tc = ((wv & 1) << 3) + (lane & 7);    // 0..15, 8 cols each
  const int row0 = blockIdx.x * GBM;

  float acc[4][8];
#pragma unroll
  for (int i = 0; i < 4; ++i)
#pragma unroll
    for (int j = 0; j < 8; ++j) acc[i][j] = 0.f;

  float4 pa[2], pb[4];

#define LOAD_AB(KC)                                                                        \
  {                                                                                        \
    const float* Asrc = ((KC) < 4) ? Amean : Ax;                                           \
    const int ab = ((KC) & 3) * GBK;                                                       \
    _Pragma("unroll") for (int i = 0; i < 2; ++i) {                                        \
      const int id = tid + i * 256;                                                        \
      pa[i] = *(const float4*)(Asrc + (size_t)(row0 + (id >> 3)) * DD + ab + ((id & 7) << 2)); \
    }                                                                                      \
    _Pragma("unroll") for (int i = 0; i < 4; ++i) {                                        \
      const int id = tid + i * 256;                                                        \
      const int gk = (KC)*GBK + (id >> 5);                                                 \
      const float* Bsrc = (gk < DD) ? (wlT + (size_t)gk * DD) : (wrT + (size_t)(gk - DD) * DD); \
      pb[i] = *(const float4*)(Bsrc + ((id & 31) << 2));                                   \
    }                                                                                      \
  }

  LOAD_AB(0)

#pragma unroll
  for (int kc = 0; kc < 8; ++kc) {
#pragma unroll
    for (int i = 0; i < 2; ++i) {
      const int id = tid + i * 256;
      const int r = id >> 3;
      const int kk = (id & 7) << 2;
      As[(kk + 0) * ASTR + r] = pa[i].x;
      As[(kk + 1) * ASTR + r] = pa[i].y;
      As[(kk + 2) * ASTR + r] = pa[i].z;
      As[(kk + 3) * ASTR + r] = pa[i].w;
    }
#pragma unroll
    for (int i = 0; i < 4; ++i) {
      const int id = tid + i * 256;
      *(float4*)(Bs + (id >> 5) * DD + ((id & 31) << 2)) = pb[i];
    }
    __syncthreads();
    if (kc < 7) LOAD_AB(kc + 1)  // overlaps with compute below
#pragma unroll
    for (int k = 0; k < GBK; ++k) {
      const float4 a0 = *(const float4*)(As + k * ASTR + tr * 4);
      const float4 b0 = *(const float4*)(Bs + k * DD + tc * 8);
      const float4 b1 = *(const float4*)(Bs + k * DD + tc * 8 + 4);
      const float av[4] = {a0.x, a0.y, a0.z, a0.w};
      const float bv[8] = {b0.x, b0.y, b0.z, b0.w, b1.x, b1.y, b1.z, b1.w};
#pragma unroll
      for (int i2 = 0; i2 < 4; ++i2)
#pragma unroll
        for (int j2 = 0; j2 < 8; ++j2) acc[i2][j2] = fmaf(av[i2], bv[j2], acc[i2][j2]);
    }
    __syncthreads();
  }
#undef LOAD_AB

  const int c0 = tc * 8;
  const float4 bb0 = *(const float4*)(bias + c0);
  const float4 bb1 = *(const float4*)(bias + c0 + 4);
  const float4 pw0 = *(const float4*)(pw + c0);
  const float4 pw1 = *(const float4*)(pw + c0 + 4);
#pragma unroll
  for (int i = 0; i < 4; ++i) {
    const int r = row0 + tr * 4 + i;
    float4 o0, o1;
    o0.x = fmaxf(acc[i][0] + bb0.x, 0.f);
    o0.y = fmaxf(acc[i][1] + bb0.y, 0.f);
    o0.z = fmaxf(acc[i][2] + bb0.z, 0.f);
    o0.w = fmaxf(acc[i][3] + bb0.w, 0.f);
    o1.x = fmaxf(acc[i][4] + bb1.x, 0.f);
    o1.y = fmaxf(acc[i][5] + bb1.y, 0.f);
    o1.z = fmaxf(acc[i][6] + bb1.z, 0.f);
    o1.w = fmaxf(acc[i][7] + bb1.w, 0.f);
    *(float4*)(outp + (size_t)r * DD + c0) = o0;
    *(float4*)(outp + (size_t)r * DD + c0 + 4) = o1;
    float sp = o0.x * pw0.x + o0.y * pw0.y + o0.z * pw0.z + o0.w * pw0.w +
               o1.x * pw1.x + o1.y * pw1.y + o1.z * pw1.z + o1.w * pw1.w;
    s_part[(tr * 4 + i) * 17 + tc] = sp;
  }
  __syncthreads();
  if (tid < 64) {
    float s = 0.f;
#pragma unroll
    for (int j = 0; j < 16; ++j) s += s_part[tid * 17 + j];
    sraw[row0 + tid] = s;
  }
}

// ---------------- topk: rank count on precomputed raw scores ----------------
// one block per graph, 512 threads; thread n = node n.

__global__ __launch_bounds__(512) void topk_kernel(const float* __restrict__ sraw,
                                                   const float* __restrict__ pw,
                                                   int* __restrict__ mask,
                                                   float* __restrict__ tbuf,
                                                   const int kk) {
  __shared__ float s_sc[NPER];
  __shared__ float s_norm;
  const int g = blockIdx.x;
  const int tid = threadIdx.x;
  const int lane = tid & 63;

  if (tid < 64) {
    const float v0 = pw[lane], v1 = pw[lane + 64];
    float p = v0 * v0 + v1 * v1;
#pragma unroll
    for (int o = 32; o > 0; o >>= 1) p += __shfl_down(p, o);
    if (lane == 0) s_norm = 1.f / (sqrtf(p) + 1e-16f);
  }
  __syncthreads();
  const int node = g * NPER + tid;
  const float s = mask[node] ? sraw[node] * s_norm : -INFINITY;
  s_sc[tid] = s;
  __syncthreads();

  // exact top-k via rank counting (stable tie-break by index = lax.top_k)
  int rank = 0;
  for (int j = 0; j < NPER; ++j) {
    const float sj = s_sc[j];
    rank += (sj > s || (sj == s && j < tid)) ? 1 : 0;
  }
  const int sel = (rank < kk) ? 1 : 0;
  mask[node] = sel;
  tbuf[node] = sel ? tanhf(s) : 0.f;
}

// ---------------- scale + partial readout ----------------
// 512 blocks = 4 per graph (128 nodes each), 256 threads. Zeroes unselected
// rows (t=0), tanh-scales selected, partial max/sum -> zp[block][256].

__global__ __launch_bounds__(256) void scale_readout_kernel(float* __restrict__ h,
                                                            const float* __restrict__ tbuf,
                                                            const int* __restrict__ mask,
                                                            float* __restrict__ zp) {
  __shared__ float red[4 * 128];
  const int b = blockIdx.x;
  const int g = b >> 2;
  const int q = b & 3;
  const int tid = threadIdx.x;
  const int fcol = tid & 127;
  const int off = tid >> 7;  // 0..1
  float pmax = -INFINITY;
  float psum = 0.f;
  const int nbase = g * NPER + q * 128;
  for (int i = 0; i < 64; ++i) {
    const int n = nbase + off + 2 * i;
    float* hp = h + (size_t)n * DD + fcol;
    const float t = tbuf[n];  // 0 for unselected
    const float v = *hp * t;
    *hp = v;
    psum += v;
    if (mask[n]) pmax = fmaxf(pmax, v);
  }
  red[off * 128 + fcol] = pmax;
  red[256 + off * 128 + fcol] = psum;
  __syncthreads();
  if (tid < 128) {
    float* row = zp + (size_t)b * 256;
    row[tid] = fmaxf(red[tid], red[128 + tid]);
    row[128 + tid] = red[256 + tid] + red[384 + tid];
  }
}

// ---------------- MLP head (reduces 4 partials/graph/layer) ----------------

__global__ __launch_bounds__(128) void mlp_kernel(const float* __restrict__ zpart,
                                                  const float* __restrict__ w1,
                                                  const float* __restrict__ b1,
                                                  const float* __restrict__ w2,
                                                  const float* __restrict__ b2,
                                                  const float* __restrict__ w3,
                                                  const float* __restrict__ b3,
                                                  float* __restrict__ out,
                                                  const float ik0, const float ik1,
                                                  const float ik2) {
  __shared__ float z[256];
  __shared__ float h1[128];
  __shared__ float h2[64];
  const int g = blockIdx.x;
  const int t = threadIdx.x;
  const float iks[3] = {ik0, ik1, ik2};
  float zmax = 0.f, zmean = 0.f;
#pragma unroll
  for (int l = 0; l < 3; ++l) {
    const float* zp = zpart + ((size_t)l * 512 + g * 4) * 256;
    zmax += fmaxf(fmaxf(zp[t], zp[256 + t]), fmaxf(zp[512 + t], zp[768 + t]));
    zmean += (zp[128 + t] + zp[384 + t] + zp[640 + t] + zp[896 + t]) * iks[l];
  }
  z[t] = zmax;
  z[128 + t] = zmean;
  __syncthreads();
  float a = b1[t];
  for (int k = 0; k < 256; ++k) a = fmaf(z[k], w1[t * 256 + k], a);
  h1[t] = fmaxf(a, 0.f);
  __syncthreads();
  if (t < 64) {
    float a2 = b2[t];
    for (int k = 0; k < 128; ++k) a2 = fmaf(h1[k], w2[t * 128 + k], a2);
    h2[t] = fmaxf(a2, 0.f);
  }
  __syncthreads();
  if (t == 0) {
    float a3 = b3[0];
    for (int k = 0; k < 64; ++k) a3 = fmaf(h2[k], w3[k], a3);
    out[g] = 1.f / (1.f + expf(-a3));
  }
}

// ---------------- launch ----------------

extern "C" void kernel_launch(void* const* d_in, const int* in_sizes, int n_in,
                              void* d_out, int out_size, void* d_ws, size_t ws_size,
                              hipStream_t stream) {
  (void)in_sizes; (void)n_in; (void)out_size; (void)ws_size;
  const float* x_in = (const float*)d_in[0];
  const int* ei = (const int*)d_in[1];
  const float* wl[3] = {(const float*)d_in[2], (const float*)d_in[6], (const float*)d_in[10]};
  const float* cbl[3] = {(const float*)d_in[3], (const float*)d_in[7], (const float*)d_in[11]};
  const float* wr[3] = {(const float*)d_in[4], (const float*)d_in[8], (const float*)d_in[12]};
  const float* pw[3] = {(const float*)d_in[5], (const float*)d_in[9], (const float*)d_in[13]};
  const float* l1w = (const float*)d_in[14];
  const float* l1b = (const float*)d_in[15];
  const float* l2w = (const float*)d_in[16];
  const float* l2b = (const float*)d_in[17];
  const float* l3w = (const float*)d_in[18];
  const float* l3b = (const float*)d_in[19];
  float* out = (float*)d_out;

  char* w = (char*)d_ws;
  int* counts = (int*)(w + 0 * (1 << 20));    // dead after setup
  float* tbuf = (float*)(w + 0 * (1 << 20));  // reuses counts (256KB)
  int* off = (int*)(w + 1 * (1 << 20));
  int* cursor = (int*)(w + 2 * (1 << 20));    // dead after setup
  float* sraw = (float*)(w + 2 * (1 << 20)); // reuses cursor (256KB)
  int* mask = (int*)(w + 3 * (1 << 20));
  float* zpart = (float*)(w + 4 * (1 << 20));          // 3*512*256*4 = 1.5MB (4..5.5MB)
  float* wT = (float*)(w + 5 * (1 << 20) + (1 << 19)); // 6*64KB at 5.5MB
  int* ssrc = (int*)(w + 6 * (1 << 20));               // 2MB
  float* mean = (float*)(w + (size_t)8 * (1 << 20));   // 32MB
  float* hA = (float*)(w + (size_t)40 * (1 << 20));    // 32MB
  float* hB = (float*)(w + (size_t)72 * (1 << 20));    // 32MB (total 104MB)

  init_kernel<<<NND / 256, 256, 0, stream>>>(counts, mask);
  hist_kernel<<<NED / 256, 256, 0, stream>>>(ei, counts);
  scan_kernel<<<1, 1024, 0, stream>>>(counts, off, cursor);
  scatter_kernel<<<NED / 256, 256, 0, stream>>>(ei, cursor, ssrc);
  transpose6_kernel<<<6, 256, 0, stream>>>(wl[0], wr[0], wl[1], wr[1], wl[2], wr[2], wT);

  const int ks[3] = {410, 328, 263};
  const float* xl = x_in;
  float* houts[3] = {hA, hB, hA};
  for (int l = 0; l < 3; ++l) {
    float* hout = houts[l];
    if (l == 0)
      agg_kernel_t<0><<<NND / 4, 256, 0, stream>>>(xl, mask, off, ssrc, mean);
    else
      agg_kernel_t<1><<<NND / 4, 256, 0, stream>>>(xl, mask, off, ssrc, mean);
    gemm_kernel<<<NND / GBM, 256, 0, stream>>>(mean, xl, wT + (size_t)(2 * l) * DD * DD,
                                               wT + (size_t)(2 * l + 1) * DD * DD, cbl[l],
                                               pw[l], hout, sraw);
    topk_kernel<<<NGR, 512, 0, stream>>>(sraw, pw[l], mask, tbuf, ks[l]);
    scale_readout_kernel<<<NGR * 4, 256, 0, stream>>>(hout, tbuf, mask,
                                                      zpart + (size_t)l * 512 * 256);
    xl = hout;
  }
  mlp_kernel<<<NGR, 128, 0, stream>>>(zpart, l1w, l1b, l2w, l2b, l3w, l3b, out,
                                      1.f / 410.f, 1.f / 328.f, 1.f / 263.f);
}

// Round 5
// 503.749 us; speedup vs baseline: 3.3380x; 1.2074x over previous
//
#include <hip/hip_runtime.h>
#include <math.h>

#define NND 65536   // total nodes
#define NPER 512    // nodes per graph
#define NGR 128     // graphs (B)
#define DD 128      // feature dim
#define NED 524288  // edges

typedef __attribute__((ext_vector_type(8))) short short8;
typedef __attribute__((ext_vector_type(4))) float f32x4;

__device__ __forceinline__ unsigned short f2b(float f) {
  unsigned u = __float_as_uint(f);
  return (unsigned short)((u + 0x7FFFu + ((u >> 16) & 1u)) >> 16);
}
__device__ __forceinline__ float b2f(unsigned short h) {
  return __uint_as_float(((unsigned)h) << 16);
}

// ---------------- CSR build ----------------

__global__ __launch_bounds__(256) void init_kernel(int* __restrict__ counts,
                                                   int* __restrict__ mask) {
  int i = blockIdx.x * 256 + threadIdx.x;
  counts[i] = 0;
  mask[i] = 1;
}

__global__ __launch_bounds__(256) void hist_kernel(const int* __restrict__ ei,
                                                   int* __restrict__ counts) {
  int e = blockIdx.x * 256 + threadIdx.x;
  atomicAdd(&counts[ei[NED + e]], 1);
}

__global__ __launch_bounds__(1024) void scan_kernel(const int* __restrict__ counts,
                                                    int* __restrict__ off,
                                                    int* __restrict__ cursor) {
  __shared__ int part[1024];
  int t = threadIdx.x;
  int base = t * 64;
  int s = 0;
  for (int i = 0; i < 64; ++i) s += counts[base + i];
  part[t] = s;
  __syncthreads();
  for (int d = 1; d < 1024; d <<= 1) {
    int v = (t >= d) ? part[t - d] : 0;
    __syncthreads();
    part[t] += v;
    __syncthreads();
  }
  int run = (t == 0) ? 0 : part[t - 1];
  for (int i = 0; i < 64; ++i) {
    off[base + i] = run;
    cursor[base + i] = run;
    run += counts[base + i];
  }
  if (t == 1023) off[NND] = run;
}

__global__ __launch_bounds__(256) void scatter_kernel(const int* __restrict__ ei,
                                                      int* __restrict__ cursor,
                                                      int* __restrict__ ssrc) {
  int e = blockIdx.x * 256 + threadIdx.x;
  int dst = ei[NED + e];
  int pos = atomicAdd(&cursor[dst], 1);
  ssrc[pos] = ei[e];
}

// ---------------- weight prep: W = [wl^T; wr^T] as bf16 hi/lo, [n][k] ----------------
// wl.T[k][n] = wl[n][k]  ->  Wcat[n][k] = k<128 ? wl[n][k] : wr[n][k-128]

__global__ __launch_bounds__(256) void prepw_kernel(
    const float* __restrict__ wl0, const float* __restrict__ wr0,
    const float* __restrict__ wl1, const float* __restrict__ wr1,
    const float* __restrict__ wl2, const float* __restrict__ wr2,
    unsigned short* __restrict__ Whi, unsigned short* __restrict__ Wlo) {
  const float* wls[3] = {wl0, wl1, wl2};
  const float* wrs[3] = {wr0, wr1, wr2};
  int e = blockIdx.x * 256 + threadIdx.x;  // 3*128*256 = 98304
  int l = e >> 15;
  int rk = e & 32767;
  int n = rk >> 8;
  int k = rk & 255;
  const float* src = (k < 128) ? wls[l] : wrs[l];
  float v = src[n * DD + (k & 127)];
  unsigned short hi = f2b(v);
  float lo = v - b2f(hi);
  Whi[e] = hi;
  Wlo[e] = f2b(lo);
}

// ---------------- mask-gated mean aggregation ----------------
// One wave per dst; 64-edge index batches broadcast via shfl; two 32-lane
// halves gather different edges as float4. Dead src rows are ZERO so no mask
// guard on the sum; deg via ballot. XCD swizzle keeps a graph's x-slice in
// one XCD's L2.

template <int CM>
__global__ __launch_bounds__(256) void agg_kernel_t(const float* __restrict__ x,
                                                    const int* __restrict__ mask,
                                                    const int* __restrict__ off,
                                                    const int* __restrict__ ssrc,
                                                    float* __restrict__ mean) {
  const int wave = threadIdx.x >> 6;
  const int lane = threadIdx.x & 63;
  const int half = lane >> 5;
  const int l = lane & 31;
  const int bid = blockIdx.x;
  const int xcd = bid & 7;
  const int slot = bid >> 3;
  const int graph = xcd * 16 + (slot >> 7);
  const int within = slot & 127;
  const int dst = graph * NPER + within * 4 + wave;

  if (CM && !mask[dst]) {
    if (lane < 32) *(float4*)(mean + (size_t)dst * DD + l * 4) = make_float4(0.f, 0.f, 0.f, 0.f);
    return;
  }
  const int beg = off[dst], end = off[dst + 1];
  float4 acc = make_float4(0.f, 0.f, 0.f, 0.f);
  int deg = 0;
  for (int base = beg; base < end; base += 64) {
    const int n = min(64, end - base);
    int sv = 0, mv = 0;
    if (lane < n) {
      sv = ssrc[base + lane];
      if (CM) mv = mask[sv];
    }
    if (CM)
      deg += (int)__popcll(__ballot(mv != 0));
    else
      deg += n;
    for (int j = half; j < n; j += 2) {
      const int s = __shfl(sv, j);
      const float4 v = *(const float4*)(x + (size_t)s * DD + l * 4);
      acc.x += v.x;
      acc.y += v.y;
      acc.z += v.z;
      acc.w += v.w;
    }
  }
  acc.x += __shfl(acc.x, lane ^ 32);
  acc.y += __shfl(acc.y, lane ^ 32);
  acc.z += __shfl(acc.z, lane ^ 32);
  acc.w += __shfl(acc.w, lane ^ 32);
  const float inv = 1.f / (float)max(deg, 1);
  if (lane < 32) {
    float4 m;
    m.x = acc.x * inv;
    m.y = acc.y * inv;
    m.z = acc.z * inv;
    m.w = acc.w * inv;
    *(float4*)(mean + (size_t)dst * DD + l * 4) = m;
  }
}

// ---------------- MFMA bf16x3 GEMM + score epilogue ----------------
// h = relu([mean|x] @ W + bl), W pre-split bf16 hi/lo [n=128][k=256].
// bf16x3: C ~= Ah*Bh + Ah*Bl + Al*Bh (rel err ~4e-6).
// BM=64, BN=128, BK=32, 256 thr = 4 waves; wave w takes cols [w*32, w*32+32)
// (2 n-tiles) x all 64 rows (4 m-tiles) of 16x16x32 MFMA tiles.
// LDS stride 40 shorts (80B, 16B-aligned rows, <=2-way banks).

#define GBM 64
#define WSTR 40

__global__ __launch_bounds__(256) void gemm_kernel(
    const float* __restrict__ Amean, const float* __restrict__ Ax,
    const unsigned short* __restrict__ Whi, const unsigned short* __restrict__ Wlo,
    const float* __restrict__ bias, const float* __restrict__ pw,
    float* __restrict__ outp, float* __restrict__ sraw) {
  __shared__ short Ah[GBM * WSTR];
  __shared__ short Al[GBM * WSTR];
  __shared__ short Bh[DD * WSTR];
  __shared__ short Bl[DD * WSTR];
  __shared__ float s_sp[4][GBM];
  const int tid = threadIdx.x;
  const int wv = tid >> 6;
  const int lane = tid & 63;
  const int q = lane >> 4;    // quad 0..3
  const int li = lane & 15;
  const int wcol0 = wv * 32;
  const int row0 = blockIdx.x * GBM;

  f32x4 acc[4][2];
#pragma unroll
  for (int m = 0; m < 4; ++m)
#pragma unroll
    for (int n = 0; n < 2; ++n) acc[m][n] = (f32x4){0.f, 0.f, 0.f, 0.f};

  float4 pa[2];
  uint4 ph[2], pl[2];

#define LOADCH(KC)                                                                   \
  {                                                                                  \
    const float* Asrc = ((KC) < 4) ? Amean : Ax;                                     \
    const int cb = ((KC) & 3) * 32;                                                  \
    _Pragma("unroll") for (int i = 0; i < 2; ++i) {                                  \
      const int id = tid + i * 256;                                                  \
      pa[i] = *(const float4*)(Asrc + (size_t)(row0 + (id >> 3)) * DD + cb + ((id & 7) << 2)); \
    }                                                                                \
    _Pragma("unroll") for (int i = 0; i < 2; ++i) {                                  \
      const int u = tid + i * 256;                                                   \
      const int ga = (u >> 2) * 256 + (KC)*32 + ((u & 3) << 3);                      \
      ph[i] = *(const uint4*)(Whi + ga);                                             \
      pl[i] = *(const uint4*)(Wlo + ga);                                             \
    }                                                                                \
  }

  LOADCH(0)

#pragma unroll
  for (int kc = 0; kc < 8; ++kc) {
    // stage A (fp32 -> bf16 hi/lo) and W (already bf16) into LDS
#pragma unroll
    for (int i = 0; i < 2; ++i) {
      const int id = tid + i * 256;
      const int r = id >> 3;
      const int kk = (id & 7) << 2;
      ushort4 hv, lv;
      hv.x = f2b(pa[i].x); lv.x = f2b(pa[i].x - b2f(hv.x));
      hv.y = f2b(pa[i].y); lv.y = f2b(pa[i].y - b2f(hv.y));
      hv.z = f2b(pa[i].z); lv.z = f2b(pa[i].z - b2f(hv.z));
      hv.w = f2b(pa[i].w); lv.w = f2b(pa[i].w - b2f(hv.w));
      *(ushort4*)(Ah + r * WSTR + kk) = hv;
      *(ushort4*)(Al + r * WSTR + kk) = lv;
    }
#pragma unroll
    for (int i = 0; i < 2; ++i) {
      const int u = tid + i * 256;
      const int n = u >> 2;
      const int kk = (u & 3) << 3;
      *(uint4*)(Bh + n * WSTR + kk) = ph[i];
      *(uint4*)(Bl + n * WSTR + kk) = pl[i];
    }
    __syncthreads();
    if (kc < 7) LOADCH(kc + 1)  // prefetch overlaps MFMA below

    short8 ah[4], al[4], bh[2], bl[2];
#pragma unroll
    for (int m = 0; m < 4; ++m) {
      const int ad = (m * 16 + li) * WSTR + q * 8;
      ah[m] = *(const short8*)(Ah + ad);
      al[m] = *(const short8*)(Al + ad);
    }
#pragma unroll
    for (int n = 0; n < 2; ++n) {
      const int bd = (wcol0 + n * 16 + li) * WSTR + q * 8;
      bh[n] = *(const short8*)(Bh + bd);
      bl[n] = *(const short8*)(Bl + bd);
    }
#pragma unroll
    for (int m = 0; m < 4; ++m)
#pragma unroll
      for (int n = 0; n < 2; ++n) {
        acc[m][n] = __builtin_amdgcn_mfma_f32_16x16x32_bf16(ah[m], bh[n], acc[m][n], 0, 0, 0);
        acc[m][n] = __builtin_amdgcn_mfma_f32_16x16x32_bf16(ah[m], bl[n], acc[m][n], 0, 0, 0);
        acc[m][n] = __builtin_amdgcn_mfma_f32_16x16x32_bf16(al[m], bh[n], acc[m][n], 0, 0, 0);
      }
    __syncthreads();
  }
#undef LOADCH

  // epilogue: bias+relu, store h, fused score partials
  // C/D layout (verified m89): col = lane&15, row = quad*4 + reg
  const int c0 = wcol0 + li;
  const int c1 = wcol0 + 16 + li;
  const float b0 = bias[c0], b1 = bias[c1];
  const float p0 = pw[c0], p1 = pw[c1];
  float sp[16];
#pragma unroll
  for (int m = 0; m < 4; ++m) {
#pragma unroll
    for (int i = 0; i < 4; ++i) {
      const int r = row0 + m * 16 + q * 4 + i;
      const float v0 = fmaxf(acc[m][0][i] + b0, 0.f);
      const float v1 = fmaxf(acc[m][1][i] + b1, 0.f);
      outp[(size_t)r * DD + c0] = v0;
      outp[(size_t)r * DD + c1] = v1;
      sp[m * 4 + i] = v0 * p0 + v1 * p1;
    }
  }
#pragma unroll
  for (int e = 0; e < 16; ++e) {
    sp[e] += __shfl_xor(sp[e], 1);
    sp[e] += __shfl_xor(sp[e], 2);
    sp[e] += __shfl_xor(sp[e], 4);
    sp[e] += __shfl_xor(sp[e], 8);
  }
  if (li == 0) {
#pragma unroll
    for (int e = 0; e < 16; ++e) s_sp[wv][(e >> 2) * 16 + q * 4 + (e & 3)] = sp[e];
  }
  __syncthreads();
  if (tid < GBM)
    sraw[row0 + tid] = s_sp[0][tid] + s_sp[1][tid] + s_sp[2][tid] + s_sp[3][tid];
}

// ---------------- merged topk + scale + partial readout ----------------
// 512 blocks = 4 per graph, 256 threads. Each block rank-counts its 128 nodes
// against all 512 scores (from sraw, prev-mask gated), writes NEW mask
// (ping-pong buffer), tanh-scales/zeroes its rows, partial max/sum -> zp.

__global__ __launch_bounds__(256) void pool_kernel(float* __restrict__ h,
                                                   const float* __restrict__ sraw,
                                                   const float* __restrict__ pw,
                                                   const int* __restrict__ maskP,
                                                   int* __restrict__ maskN,
                                                   float* __restrict__ zp,
                                                   const int kk) {
  __shared__ float s_sc[NPER];
  __shared__ float s_t[128];
  __shared__ unsigned char s_sel[128];
  __shared__ float red[4 * 128];
  __shared__ float s_norm;
  const int b = blockIdx.x;
  const int g = b >> 2;
  const int q = b & 3;
  const int tid = threadIdx.x;
  const int lane = tid & 63;

  if (tid < 64) {
    const float v0 = pw[lane], v1 = pw[lane + 64];
    float p = v0 * v0 + v1 * v1;
#pragma unroll
    for (int o = 32; o > 0; o >>= 1) p += __shfl_down(p, o);
    if (lane == 0) s_norm = 1.f / (sqrtf(p) + 1e-16f);
  }
  __syncthreads();
  const float inv_norm = s_norm;
#pragma unroll
  for (int i = 0; i < 2; ++i) {
    const int n = tid + i * 256;
    const int node = g * NPER + n;
    s_sc[n] = maskP[node] ? sraw[node] * inv_norm : -INFINITY;
  }
  __syncthreads();

  if (tid < 128) {
    const int n = q * 128 + tid;
    const float s = s_sc[n];
    int rank = 0;
    for (int j = 0; j < NPER; ++j) {
      const float sj = s_sc[j];
      rank += (sj > s || (sj == s && j < n)) ? 1 : 0;
    }
    const int sel = (rank < kk) ? 1 : 0;
    maskN[g * NPER + n] = sel;
    s_sel[tid] = (unsigned char)sel;
    s_t[tid] = sel ? tanhf(s) : 0.f;
  }
  __syncthreads();

  const int fcol = tid & 127;
  const int off = tid >> 7;  // 0..1
  float pmax = -INFINITY;
  float psum = 0.f;
  const int nbase = g * NPER + q * 128;
  for (int i = 0; i < 64; ++i) {
    const int nl = off + 2 * i;
    float* hp = h + (size_t)(nbase + nl) * DD + fcol;
    const float t = s_t[nl];  // 0 for unselected -> zeroes row
    const float v = *hp * t;
    *hp = v;
    psum += v;
    if (s_sel[nl]) pmax = fmaxf(pmax, v);
  }
  red[off * 128 + fcol] = pmax;
  red[256 + off * 128 + fcol] = psum;
  __syncthreads();
  if (tid < 128) {
    float* row = zp + (size_t)b * 256;
    row[tid] = fmaxf(red[tid], red[128 + tid]);
    row[128 + tid] = red[256 + tid] + red[384 + tid];
  }
}

// ---------------- MLP head (reduces 4 partials/graph/layer) ----------------

__global__ __launch_bounds__(128) void mlp_kernel(const float* __restrict__ zpart,
                                                  const float* __restrict__ w1,
                                                  const float* __restrict__ b1,
                                                  const float* __restrict__ w2,
                                                  const float* __restrict__ b2,
                                                  const float* __restrict__ w3,
                                                  const float* __restrict__ b3,
                                                  float* __restrict__ out,
                                                  const float ik0, const float ik1,
                                                  const float ik2) {
  __shared__ float z[256];
  __shared__ float h1[128];
  __shared__ float h2[64];
  const int g = blockIdx.x;
  const int t = threadIdx.x;
  const float iks[3] = {ik0, ik1, ik2};
  float zmax = 0.f, zmean = 0.f;
#pragma unroll
  for (int l = 0; l < 3; ++l) {
    const float* zp = zpart + ((size_t)l * 512 + g * 4) * 256;
    zmax += fmaxf(fmaxf(zp[t], zp[256 + t]), fmaxf(zp[512 + t], zp[768 + t]));
    zmean += (zp[128 + t] + zp[384 + t] + zp[640 + t] + zp[896 + t]) * iks[l];
  }
  z[t] = zmax;
  z[128 + t] = zmean;
  __syncthreads();
  float a = b1[t];
  for (int k = 0; k < 256; ++k) a = fmaf(z[k], w1[t * 256 + k], a);
  h1[t] = fmaxf(a, 0.f);
  __syncthreads();
  if (t < 64) {
    float a2 = b2[t];
    for (int k = 0; k < 128; ++k) a2 = fmaf(h1[k], w2[t * 128 + k], a2);
    h2[t] = fmaxf(a2, 0.f);
  }
  __syncthreads();
  if (t == 0) {
    float a3 = b3[0];
    for (int k = 0; k < 64; ++k) a3 = fmaf(h2[k], w3[k], a3);
    out[g] = 1.f / (1.f + expf(-a3));
  }
}

// ---------------- launch ----------------

extern "C" void kernel_launch(void* const* d_in, const int* in_sizes, int n_in,
                              void* d_out, int out_size, void* d_ws, size_t ws_size,
                              hipStream_t stream) {
  (void)in_sizes; (void)n_in; (void)out_size; (void)ws_size;
  const float* x_in = (const float*)d_in[0];
  const int* ei = (const int*)d_in[1];
  const float* wl[3] = {(const float*)d_in[2], (const float*)d_in[6], (const float*)d_in[10]};
  const float* cbl[3] = {(const float*)d_in[3], (const float*)d_in[7], (const float*)d_in[11]};
  const float* wr[3] = {(const float*)d_in[4], (const float*)d_in[8], (const float*)d_in[12]};
  const float* pw[3] = {(const float*)d_in[5], (const float*)d_in[9], (const float*)d_in[13]};
  const float* l1w = (const float*)d_in[14];
  const float* l1b = (const float*)d_in[15];
  const float* l2w = (const float*)d_in[16];
  const float* l2b = (const float*)d_in[17];
  const float* l3w = (const float*)d_in[18];
  const float* l3b = (const float*)d_in[19];
  float* out = (float*)d_out;

  char* w = (char*)d_ws;
  int* counts = (int*)(w + 0 * (1 << 20));  // dead after setup
  int* off = (int*)(w + 1 * (1 << 20));
  int* cursor = (int*)(w + 2 * (1 << 20));  // dead after scatter
  float* sraw = (float*)(w + 2 * (1 << 20));  // reuses cursor (256KB)
  int* maskA = (int*)(w + 3 * (1 << 20));                // 256KB
  int* maskB = (int*)(w + 3 * (1 << 20) + (1 << 19));    // 256KB
  float* zpart = (float*)(w + 4 * (1 << 20));            // 1.5MB (4..5.5MB)
  unsigned short* Whi = (unsigned short*)(w + 5 * (1 << 20) + (1 << 19));        // 192KB
  unsigned short* Wlo = (unsigned short*)(w + 5 * (1 << 20) + 3 * (1 << 18));    // 192KB
  int* ssrc = (int*)(w + 6 * (1 << 20));               // 2MB
  float* mean = (float*)(w + (size_t)8 * (1 << 20));   // 32MB
  float* hA = (float*)(w + (size_t)40 * (1 << 20));    // 32MB
  float* hB = (float*)(w + (size_t)72 * (1 << 20));    // 32MB (total 104MB)

  init_kernel<<<NND / 256, 256, 0, stream>>>(counts, maskA);
  hist_kernel<<<NED / 256, 256, 0, stream>>>(ei, counts);
  scan_kernel<<<1, 1024, 0, stream>>>(counts, off, cursor);
  scatter_kernel<<<NED / 256, 256, 0, stream>>>(ei, cursor, ssrc);
  prepw_kernel<<<384, 256, 0, stream>>>(wl[0], wr[0], wl[1], wr[1], wl[2], wr[2], Whi, Wlo);

  const int ks[3] = {410, 328, 263};
  const float* xl = x_in;
  float* houts[3] = {hA, hB, hA};
  // mask ping-pong: layer l reads mprev, pool writes mnext
  int* mprev[3] = {maskA, maskB, maskA};
  int* mnext[3] = {maskB, maskA, maskB};
  for (int l = 0; l < 3; ++l) {
    float* hout = houts[l];
    if (l == 0)
      agg_kernel_t<0><<<NND / 4, 256, 0, stream>>>(xl, mprev[l], off, ssrc, mean);
    else
      agg_kernel_t<1><<<NND / 4, 256, 0, stream>>>(xl, mprev[l], off, ssrc, mean);
    gemm_kernel<<<NND / GBM, 256, 0, stream>>>(mean, xl, Whi + (size_t)l * 32768,
                                               Wlo + (size_t)l * 32768, cbl[l], pw[l],
                                               hout, sraw);
    pool_kernel<<<NGR * 4, 256, 0, stream>>>(hout, sraw, pw[l], mprev[l], mnext[l],
                                             zpart + (size_t)l * 512 * 256, ks[l]);
    xl = hout;
  }
  mlp_kernel<<<NGR, 128, 0, stream>>>(zpart, l1w, l1b, l2w, l2b, l3w, l3b, out,
                                      1.f / 410.f, 1.f / 328.f, 1.f / 263.f);
}

// Round 6
// 427.244 us; speedup vs baseline: 3.9357x; 1.1791x over previous
//
#include <hip/hip_runtime.h>
#include <math.h>

#define NND 65536   // total nodes
#define NPER 512    // nodes per graph
#define NGR 128     // graphs (B)
#define DD 128      // feature dim
#define NED 524288  // edges

typedef __attribute__((ext_vector_type(8))) short short8;
typedef __attribute__((ext_vector_type(4))) float f32x4;

__device__ __forceinline__ unsigned short f2b(float f) {
  unsigned u = __float_as_uint(f);
  return (unsigned short)((u + 0x7FFFu + ((u >> 16) & 1u)) >> 16);
}
__device__ __forceinline__ float b2f(unsigned short h) {
  return __uint_as_float(((unsigned)h) << 16);
}

// ---------------- CSR build ----------------

__global__ __launch_bounds__(256) void init_kernel(int* __restrict__ counts,
                                                   int* __restrict__ mask) {
  int i = blockIdx.x * 256 + threadIdx.x;
  counts[i] = 0;
  mask[i] = 1;
}

__global__ __launch_bounds__(256) void hist_kernel(const int* __restrict__ ei,
                                                   int* __restrict__ counts) {
  int e = blockIdx.x * 256 + threadIdx.x;
  atomicAdd(&counts[ei[NED + e]], 1);
}

__global__ __launch_bounds__(1024) void scan_kernel(const int* __restrict__ counts,
                                                    int* __restrict__ off,
                                                    int* __restrict__ cursor) {
  __shared__ int part[1024];
  int t = threadIdx.x;
  int base = t * 64;
  int s = 0;
  for (int i = 0; i < 64; ++i) s += counts[base + i];
  part[t] = s;
  __syncthreads();
  for (int d = 1; d < 1024; d <<= 1) {
    int v = (t >= d) ? part[t - d] : 0;
    __syncthreads();
    part[t] += v;
    __syncthreads();
  }
  int run = (t == 0) ? 0 : part[t - 1];
  for (int i = 0; i < 64; ++i) {
    off[base + i] = run;
    cursor[base + i] = run;
    run += counts[base + i];
  }
  if (t == 1023) off[NND] = run;
}

__global__ __launch_bounds__(256) void scatter_kernel(const int* __restrict__ ei,
                                                      int* __restrict__ cursor,
                                                      int* __restrict__ ssrc) {
  int e = blockIdx.x * 256 + threadIdx.x;
  int dst = ei[NED + e];
  int pos = atomicAdd(&cursor[dst], 1);
  ssrc[pos] = ei[e];
}

// ---------------- weight prep: bf16 hi/lo in MFMA-FRAGMENT order ----------------
// Layout: Whi[l][kc][nt][lane][j]  (kc=K/32 chunk, nt=N/16 tile, lane=q*16+li,
// j=0..7).  Element = Wcat[n=nt*16+li][k=kc*32+q*8+j], Wcat=[wl^T;wr^T][n][k].
// gemm reads B as ONE contiguous 1KB/wave global load -> no B LDS at all.

__global__ __launch_bounds__(256) void prepw_kernel(
    const float* __restrict__ wl0, const float* __restrict__ wr0,
    const float* __restrict__ wl1, const float* __restrict__ wr1,
    const float* __restrict__ wl2, const float* __restrict__ wr2,
    unsigned short* __restrict__ Whi, unsigned short* __restrict__ Wlo) {
  const float* wls[3] = {wl0, wl1, wl2};
  const float* wrs[3] = {wr0, wr1, wr2};
  int e = blockIdx.x * 256 + threadIdx.x;  // 3*32768
  int l = e >> 15;
  int o = e & 32767;
  int j = o & 7;
  int lane = (o >> 3) & 63;
  int nt = (o >> 9) & 7;
  int kc = o >> 12;
  int li = lane & 15, q = lane >> 4;
  int n = nt * 16 + li;
  int k = kc * 32 + q * 8 + j;
  const float* src = (k < 128) ? wls[l] : wrs[l];
  float v = src[n * DD + (k & 127)];
  unsigned short hi = f2b(v);
  float lo = v - b2f(hi);
  Whi[e] = hi;
  Wlo[e] = f2b(lo);
}

// ---------------- mask-gated mean aggregation ----------------
// One wave per dst; 64-edge index batches broadcast via shfl; two 32-lane
// halves gather different edges as float4. Dead src rows are ZERO so no mask
// guard on the sum; deg via ballot. XCD swizzle keeps a graph's x-slice in
// one XCD's L2.

template <int CM>
__global__ __launch_bounds__(256) void agg_kernel_t(const float* __restrict__ x,
                                                    const int* __restrict__ mask,
                                                    const int* __restrict__ off,
                                                    const int* __restrict__ ssrc,
                                                    float* __restrict__ mean) {
  const int wave = threadIdx.x >> 6;
  const int lane = threadIdx.x & 63;
  const int half = lane >> 5;
  const int l = lane & 31;
  const int bid = blockIdx.x;
  const int xcd = bid & 7;
  const int slot = bid >> 3;
  const int graph = xcd * 16 + (slot >> 7);
  const int within = slot & 127;
  const int dst = graph * NPER + within * 4 + wave;

  if (CM && !mask[dst]) {
    if (lane < 32) *(float4*)(mean + (size_t)dst * DD + l * 4) = make_float4(0.f, 0.f, 0.f, 0.f);
    return;
  }
  const int beg = off[dst], end = off[dst + 1];
  float4 acc = make_float4(0.f, 0.f, 0.f, 0.f);
  int deg = 0;
  for (int base = beg; base < end; base += 64) {
    const int n = min(64, end - base);
    int sv = 0, mv = 0;
    if (lane < n) {
      sv = ssrc[base + lane];
      if (CM) mv = mask[sv];
    }
    if (CM)
      deg += (int)__popcll(__ballot(mv != 0));
    else
      deg += n;
    for (int j = half; j < n; j += 2) {
      const int s = __shfl(sv, j);
      const float4 v = *(const float4*)(x + (size_t)s * DD + l * 4);
      acc.x += v.x;
      acc.y += v.y;
      acc.z += v.z;
      acc.w += v.w;
    }
  }
  acc.x += __shfl(acc.x, lane ^ 32);
  acc.y += __shfl(acc.y, lane ^ 32);
  acc.z += __shfl(acc.z, lane ^ 32);
  acc.w += __shfl(acc.w, lane ^ 32);
  const float inv = 1.f / (float)max(deg, 1);
  if (lane < 32) {
    float4 m;
    m.x = acc.x * inv;
    m.y = acc.y * inv;
    m.z = acc.z * inv;
    m.w = acc.w * inv;
    *(float4*)(mean + (size_t)dst * DD + l * 4) = m;
  }
}

// ---------------- MFMA bf16x3 GEMM + score epilogue ----------------
// h = relu([mean|x] @ W + bl); bf16x3: Ah*Bh + Ah*Bl + Al*Bh.
// B: fragment-ordered global loads (no LDS). A: LDS in fragment order
// [m][lane][8] -> ds_read_b128 is a linear 16B/lane sweep (conflict-free);
// ds_write_b64 staging at the bank floor. LDS 9KB (was 31KB).

#define GBM 64

__global__ __launch_bounds__(256) void gemm_kernel(
    const float* __restrict__ Amean, const float* __restrict__ Ax,
    const unsigned short* __restrict__ Whi, const unsigned short* __restrict__ Wlo,
    const float* __restrict__ bias, const float* __restrict__ pw,
    float* __restrict__ outp, float* __restrict__ sraw) {
  __shared__ short Ah[2048];  // [m][lane][8]
  __shared__ short Al[2048];
  __shared__ float s_sp[4][GBM];
  const int tid = threadIdx.x;
  const int wv = tid >> 6;
  const int lane = tid & 63;
  const int q = lane >> 4;
  const int li = lane & 15;
  const int row0 = blockIdx.x * GBM;

  // A staging dest (shorts): row r=id>>3, k-offset kb=(id&7)*4 ->
  // frag addr ((r>>4)*64 + (kb>>3)*16 + (r&15))*8 + (kb&7)
  int sdst[2];
#pragma unroll
  for (int i = 0; i < 2; ++i) {
    const int id = tid + i * 256;
    const int r = id >> 3;
    const int kb = (id & 7) << 2;
    sdst[i] = ((r >> 4) * 64 + (kb >> 3) * 16 + (r & 15)) * 8 + (kb & 7);
  }

  f32x4 acc[4][2];
#pragma unroll
  for (int m = 0; m < 4; ++m)
#pragma unroll
    for (int n = 0; n < 2; ++n) acc[m][n] = (f32x4){0.f, 0.f, 0.f, 0.f};

  float4 pa[2];
  short8 pbh[2], pbl[2];

#define LOADA(KC)                                                                    \
  {                                                                                  \
    const float* Asrc = ((KC) < 4) ? Amean : Ax;                                     \
    const int cb = ((KC) & 3) * 32;                                                  \
    _Pragma("unroll") for (int i = 0; i < 2; ++i) {                                  \
      const int id = tid + i * 256;                                                  \
      pa[i] = *(const float4*)(Asrc + (size_t)(row0 + (id >> 3)) * DD + cb + ((id & 7) << 2)); \
    }                                                                                \
  }
#define LOADB(KC)                                                                    \
  {                                                                                  \
    _Pragma("unroll") for (int n = 0; n < 2; ++n) {                                  \
      const int ga = (((KC)*8 + wv * 2 + n) * 64 + lane) * 8;                        \
      pbh[n] = *(const short8*)(Whi + ga);                                           \
      pbl[n] = *(const short8*)(Wlo + ga);                                           \
    }                                                                                \
  }

  LOADA(0) LOADB(0)

#pragma unroll
  for (int kc = 0; kc < 8; ++kc) {
    // stage A (fp32 -> bf16 hi/lo) into fragment-ordered LDS
#pragma unroll
    for (int i = 0; i < 2; ++i) {
      ushort4 hv, lv;
      hv.x = f2b(pa[i].x); lv.x = f2b(pa[i].x - b2f(hv.x));
      hv.y = f2b(pa[i].y); lv.y = f2b(pa[i].y - b2f(hv.y));
      hv.z = f2b(pa[i].z); lv.z = f2b(pa[i].z - b2f(hv.z));
      hv.w = f2b(pa[i].w); lv.w = f2b(pa[i].w - b2f(hv.w));
      *(ushort4*)(Ah + sdst[i]) = hv;
      *(ushort4*)(Al + sdst[i]) = lv;
    }
    short8 bh[2], bl[2];
    bh[0] = pbh[0]; bh[1] = pbh[1];
    bl[0] = pbl[0]; bl[1] = pbl[1];
    __syncthreads();
    short8 ah[4], al[4];
#pragma unroll
    for (int m = 0; m < 4; ++m) {
      ah[m] = *(const short8*)(Ah + (m * 64 + lane) * 8);
      al[m] = *(const short8*)(Al + (m * 64 + lane) * 8);
    }
    if (kc < 7) { LOADA(kc + 1) LOADB(kc + 1) }  // prefetch overlaps MFMA
#pragma unroll
    for (int m = 0; m < 4; ++m)
#pragma unroll
      for (int n = 0; n < 2; ++n) {
        acc[m][n] = __builtin_amdgcn_mfma_f32_16x16x32_bf16(ah[m], bh[n], acc[m][n], 0, 0, 0);
        acc[m][n] = __builtin_amdgcn_mfma_f32_16x16x32_bf16(ah[m], bl[n], acc[m][n], 0, 0, 0);
        acc[m][n] = __builtin_amdgcn_mfma_f32_16x16x32_bf16(al[m], bh[n], acc[m][n], 0, 0, 0);
      }
    __syncthreads();
  }
#undef LOADA
#undef LOADB

  // epilogue: bias+relu, store h, fused score partials
  // C/D layout (verified m89): col = lane&15, row = quad*4 + reg
  const int c0 = wv * 32 + li;
  const int c1 = wv * 32 + 16 + li;
  const float b0 = bias[c0], b1 = bias[c1];
  const float p0 = pw[c0], p1 = pw[c1];
  float sp[16];
#pragma unroll
  for (int m = 0; m < 4; ++m) {
#pragma unroll
    for (int i = 0; i < 4; ++i) {
      const int r = row0 + m * 16 + q * 4 + i;
      const float v0 = fmaxf(acc[m][0][i] + b0, 0.f);
      const float v1 = fmaxf(acc[m][1][i] + b1, 0.f);
      outp[(size_t)r * DD + c0] = v0;
      outp[(size_t)r * DD + c1] = v1;
      sp[m * 4 + i] = v0 * p0 + v1 * p1;
    }
  }
#pragma unroll
  for (int e = 0; e < 16; ++e) {
    sp[e] += __shfl_xor(sp[e], 1);
    sp[e] += __shfl_xor(sp[e], 2);
    sp[e] += __shfl_xor(sp[e], 4);
    sp[e] += __shfl_xor(sp[e], 8);
  }
  if (li == 0) {
#pragma unroll
    for (int e = 0; e < 16; ++e) s_sp[wv][(e >> 2) * 16 + q * 4 + (e & 3)] = sp[e];
  }
  __syncthreads();
  if (tid < GBM)
    sraw[row0 + tid] = s_sp[0][tid] + s_sp[1][tid] + s_sp[2][tid] + s_sp[3][tid];
}

// ---------------- merged topk + scale + partial readout ----------------
// 512 blocks = 4 per graph, 256 threads. Each block rank-counts its 128 nodes
// against all 512 scores (from sraw, prev-mask gated), writes NEW mask
// (ping-pong buffer), tanh-scales/zeroes its rows, partial max/sum -> zp.

__global__ __launch_bounds__(256) void pool_kernel(float* __restrict__ h,
                                                   const float* __restrict__ sraw,
                                                   const float* __restrict__ pw,
                                                   const int* __restrict__ maskP,
                                                   int* __restrict__ maskN,
                                                   float* __restrict__ zp,
                                                   const int kk) {
  __shared__ float s_sc[NPER];
  __shared__ float s_t[128];
  __shared__ unsigned char s_sel[128];
  __shared__ float red[4 * 128];
  __shared__ float s_norm;
  const int b = blockIdx.x;
  const int g = b >> 2;
  const int q = b & 3;
  const int tid = threadIdx.x;
  const int lane = tid & 63;

  if (tid < 64) {
    const float v0 = pw[lane], v1 = pw[lane + 64];
    float p = v0 * v0 + v1 * v1;
#pragma unroll
    for (int o = 32; o > 0; o >>= 1) p += __shfl_down(p, o);
    if (lane == 0) s_norm = 1.f / (sqrtf(p) + 1e-16f);
  }
  __syncthreads();
  const float inv_norm = s_norm;
#pragma unroll
  for (int i = 0; i < 2; ++i) {
    const int n = tid + i * 256;
    const int node = g * NPER + n;
    s_sc[n] = maskP[node] ? sraw[node] * inv_norm : -INFINITY;
  }
  __syncthreads();

  if (tid < 128) {
    const int n = q * 128 + tid;
    const float s = s_sc[n];
    int rank = 0;
    for (int j = 0; j < NPER; ++j) {
      const float sj = s_sc[j];
      rank += (sj > s || (sj == s && j < n)) ? 1 : 0;
    }
    const int sel = (rank < kk) ? 1 : 0;
    maskN[g * NPER + n] = sel;
    s_sel[tid] = (unsigned char)sel;
    s_t[tid] = sel ? tanhf(s) : 0.f;
  }
  __syncthreads();

  const int fcol = tid & 127;
  const int off = tid >> 7;  // 0..1
  float pmax = -INFINITY;
  float psum = 0.f;
  const int nbase = g * NPER + q * 128;
  for (int i = 0; i < 64; ++i) {
    const int nl = off + 2 * i;
    float* hp = h + (size_t)(nbase + nl) * DD + fcol;
    const float t = s_t[nl];  // 0 for unselected -> zeroes row
    const float v = *hp * t;
    *hp = v;
    psum += v;
    if (s_sel[nl]) pmax = fmaxf(pmax, v);
  }
  red[off * 128 + fcol] = pmax;
  red[256 + off * 128 + fcol] = psum;
  __syncthreads();
  if (tid < 128) {
    float* row = zp + (size_t)b * 256;
    row[tid] = fmaxf(red[tid], red[128 + tid]);
    row[128 + tid] = red[256 + tid] + red[384 + tid];
  }
}

// ---------------- MLP head (reduces 4 partials/graph/layer) ----------------

__global__ __launch_bounds__(128) void mlp_kernel(const float* __restrict__ zpart,
                                                  const float* __restrict__ w1,
                                                  const float* __restrict__ b1,
                                                  const float* __restrict__ w2,
                                                  const float* __restrict__ b2,
                                                  const float* __restrict__ w3,
                                                  const float* __restrict__ b3,
                                                  float* __restrict__ out,
                                                  const float ik0, const float ik1,
                                                  const float ik2) {
  __shared__ float z[256];
  __shared__ float h1[128];
  __shared__ float h2[64];
  const int g = blockIdx.x;
  const int t = threadIdx.x;
  const float iks[3] = {ik0, ik1, ik2};
  float zmax = 0.f, zmean = 0.f;
#pragma unroll
  for (int l = 0; l < 3; ++l) {
    const float* zp = zpart + ((size_t)l * 512 + g * 4) * 256;
    zmax += fmaxf(fmaxf(zp[t], zp[256 + t]), fmaxf(zp[512 + t], zp[768 + t]));
    zmean += (zp[128 + t] + zp[384 + t] + zp[640 + t] + zp[896 + t]) * iks[l];
  }
  z[t] = zmax;
  z[128 + t] = zmean;
  __syncthreads();
  float a = b1[t];
  for (int k = 0; k < 256; ++k) a = fmaf(z[k], w1[t * 256 + k], a);
  h1[t] = fmaxf(a, 0.f);
  __syncthreads();
  if (t < 64) {
    float a2 = b2[t];
    for (int k = 0; k < 128; ++k) a2 = fmaf(h1[k], w2[t * 128 + k], a2);
    h2[t] = fmaxf(a2, 0.f);
  }
  __syncthreads();
  if (t == 0) {
    float a3 = b3[0];
    for (int k = 0; k < 64; ++k) a3 = fmaf(h2[k], w3[k], a3);
    out[g] = 1.f / (1.f + expf(-a3));
  }
}

// ---------------- launch ----------------

extern "C" void kernel_launch(void* const* d_in, const int* in_sizes, int n_in,
                              void* d_out, int out_size, void* d_ws, size_t ws_size,
                              hipStream_t stream) {
  (void)in_sizes; (void)n_in; (void)out_size; (void)ws_size;
  const float* x_in = (const float*)d_in[0];
  const int* ei = (const int*)d_in[1];
  const float* wl[3] = {(const float*)d_in[2], (const float*)d_in[6], (const float*)d_in[10]};
  const float* cbl[3] = {(const float*)d_in[3], (const float*)d_in[7], (const float*)d_in[11]};
  const float* wr[3] = {(const float*)d_in[4], (const float*)d_in[8], (const float*)d_in[12]};
  const float* pw[3] = {(const float*)d_in[5], (const float*)d_in[9], (const float*)d_in[13]};
  const float* l1w = (const float*)d_in[14];
  const float* l1b = (const float*)d_in[15];
  const float* l2w = (const float*)d_in[16];
  const float* l2b = (const float*)d_in[17];
  const float* l3w = (const float*)d_in[18];
  const float* l3b = (const float*)d_in[19];
  float* out = (float*)d_out;

  char* w = (char*)d_ws;
  int* counts = (int*)(w + 0 * (1 << 20));  // dead after setup
  int* off = (int*)(w + 1 * (1 << 20));
  int* cursor = (int*)(w + 2 * (1 << 20));  // dead after scatter
  float* sraw = (float*)(w + 2 * (1 << 20));  // reuses cursor (256KB)
  int* maskA = (int*)(w + 3 * (1 << 20));                // 256KB
  int* maskB = (int*)(w + 3 * (1 << 20) + (1 << 19));    // 256KB
  float* zpart = (float*)(w + 4 * (1 << 20));            // 1.5MB (4..5.5MB)
  unsigned short* Whi = (unsigned short*)(w + 5 * (1 << 20) + (1 << 19));        // 192KB
  unsigned short* Wlo = (unsigned short*)(w + 5 * (1 << 20) + 3 * (1 << 18));    // 192KB
  int* ssrc = (int*)(w + 6 * (1 << 20));               // 2MB
  float* mean = (float*)(w + (size_t)8 * (1 << 20));   // 32MB
  float* hA = (float*)(w + (size_t)40 * (1 << 20));    // 32MB
  float* hB = (float*)(w + (size_t)72 * (1 << 20));    // 32MB (total 104MB)

  init_kernel<<<NND / 256, 256, 0, stream>>>(counts, maskA);
  hist_kernel<<<NED / 256, 256, 0, stream>>>(ei, counts);
  scan_kernel<<<1, 1024, 0, stream>>>(counts, off, cursor);
  scatter_kernel<<<NED / 256, 256, 0, stream>>>(ei, cursor, ssrc);
  prepw_kernel<<<384, 256, 0, stream>>>(wl[0], wr[0], wl[1], wr[1], wl[2], wr[2], Whi, Wlo);

  const int ks[3] = {410, 328, 263};
  const float* xl = x_in;
  float* houts[3] = {hA, hB, hA};
  // mask ping-pong: layer l reads mprev, pool writes mnext
  int* mprev[3] = {maskA, maskB, maskA};
  int* mnext[3] = {maskB, maskA, maskB};
  for (int l = 0; l < 3; ++l) {
    float* hout = houts[l];
    if (l == 0)
      agg_kernel_t<0><<<NND / 4, 256, 0, stream>>>(xl, mprev[l], off, ssrc, mean);
    else
      agg_kernel_t<1><<<NND / 4, 256, 0, stream>>>(xl, mprev[l], off, ssrc, mean);
    gemm_kernel<<<NND / GBM, 256, 0, stream>>>(mean, xl, Whi + (size_t)l * 32768,
                                               Wlo + (size_t)l * 32768, cbl[l], pw[l],
                                               hout, sraw);
    pool_kernel<<<NGR * 4, 256, 0, stream>>>(hout, sraw, pw[l], mprev[l], mnext[l],
                                             zpart + (size_t)l * 512 * 256, ks[l]);
    xl = hout;
  }
  mlp_kernel<<<NGR, 128, 0, stream>>>(zpart, l1w, l1b, l2w, l2b, l3w, l3b, out,
                                      1.f / 410.f, 1.f / 328.f, 1.f / 263.f);
}

// Round 7
// 420.037 us; speedup vs baseline: 4.0032x; 1.0172x over previous
//
#include <hip/hip_runtime.h>
#include <math.h>

#define NND 65536   // total nodes
#define NPER 512    // nodes per graph
#define NGR 128     // graphs (B)
#define DD 128      // feature dim
#define NED 524288  // edges

typedef __attribute__((ext_vector_type(8))) short short8;
typedef __attribute__((ext_vector_type(4))) float f32x4;

__device__ __forceinline__ unsigned short f2b(float f) {
  unsigned u = __float_as_uint(f);
  return (unsigned short)((u + 0x7FFFu + ((u >> 16) & 1u)) >> 16);
}
__device__ __forceinline__ float b2f(unsigned short h) {
  return __uint_as_float(((unsigned)h) << 16);
}

// ---------------- CSR build ----------------

__global__ __launch_bounds__(256) void init_kernel(int* __restrict__ counts,
                                                   float2* __restrict__ tm) {
  int i = blockIdx.x * 256 + threadIdx.x;
  counts[i] = 0;
  tm[i] = make_float2(1.f, 1.f);  // layer-0: all selected, t=1
}

__global__ __launch_bounds__(256) void hist_kernel(const int* __restrict__ ei,
                                                   int* __restrict__ counts) {
  int e = blockIdx.x * 256 + threadIdx.x;
  atomicAdd(&counts[ei[NED + e]], 1);
}

__global__ __launch_bounds__(1024) void scan_kernel(const int* __restrict__ counts,
                                                    int* __restrict__ off,
                                                    int* __restrict__ cursor) {
  __shared__ int part[1024];
  int t = threadIdx.x;
  int base = t * 64;
  int s = 0;
  const int4* c4 = (const int4*)(counts + base);
  for (int i = 0; i < 16; ++i) {
    int4 v = c4[i];
    s += v.x + v.y + v.z + v.w;
  }
  part[t] = s;
  __syncthreads();
  for (int d = 1; d < 1024; d <<= 1) {
    int v = (t >= d) ? part[t - d] : 0;
    __syncthreads();
    part[t] += v;
    __syncthreads();
  }
  int run = (t == 0) ? 0 : part[t - 1];
  for (int i = 0; i < 64; ++i) {
    off[base + i] = run;
    cursor[base + i] = run;
    run += counts[base + i];
  }
  if (t == 1023) off[NND] = run;
}

__global__ __launch_bounds__(256) void scatter_kernel(const int* __restrict__ ei,
                                                      int* __restrict__ cursor,
                                                      int* __restrict__ ssrc) {
  int e = blockIdx.x * 256 + threadIdx.x;
  int dst = ei[NED + e];
  int pos = atomicAdd(&cursor[dst], 1);
  ssrc[pos] = ei[e];
}

// ---------------- weight prep: bf16 hi/lo in MFMA-FRAGMENT order ----------------

__global__ __launch_bounds__(256) void prepw_kernel(
    const float* __restrict__ wl0, const float* __restrict__ wr0,
    const float* __restrict__ wl1, const float* __restrict__ wr1,
    const float* __restrict__ wl2, const float* __restrict__ wr2,
    unsigned short* __restrict__ Whi, unsigned short* __restrict__ Wlo) {
  const float* wls[3] = {wl0, wl1, wl2};
  const float* wrs[3] = {wr0, wr1, wr2};
  int e = blockIdx.x * 256 + threadIdx.x;  // 3*32768
  int l = e >> 15;
  int o = e & 32767;
  int j = o & 7;
  int lane = (o >> 3) & 63;
  int nt = (o >> 9) & 7;
  int kc = o >> 12;
  int li = lane & 15, q = lane >> 4;
  int n = nt * 16 + li;
  int k = kc * 32 + q * 8 + j;
  const float* src = (k < 128) ? wls[l] : wrs[l];
  float v = src[n * DD + (k & 127)];
  unsigned short hi = f2b(v);
  float lo = v - b2f(hi);
  Whi[e] = hi;
  Wlo[e] = f2b(lo);
}

// ---------------- mask-gated mean aggregation (t-deferred) ----------------
// h in memory is UNSCALED; tm[n] = {sel?1:0, sel?tanh(score):0}. Gathered rows
// are multiplied by broadcast t[src] (unselected -> t=0 -> contribute 0).
// 4 edges in flight per 32-lane half (8/wave) to cover the gather latency.

template <int CM>
__global__ __launch_bounds__(256) void agg_kernel_t(const float* __restrict__ x,
                                                    const float2* __restrict__ tm,
                                                    const int* __restrict__ off,
                                                    const int* __restrict__ ssrc,
                                                    float* __restrict__ mean) {
  const int wave = threadIdx.x >> 6;
  const int lane = threadIdx.x & 63;
  const int half = lane >> 5;
  const int l = lane & 31;
  const int bid = blockIdx.x;
  const int xcd = bid & 7;
  const int slot = bid >> 3;
  const int graph = xcd * 16 + (slot >> 7);
  const int within = slot & 127;
  const int dst = graph * NPER + within * 4 + wave;

  if (CM && tm[dst].x == 0.f) {
    if (lane < 32) *(float4*)(mean + (size_t)dst * DD + l * 4) = make_float4(0.f, 0.f, 0.f, 0.f);
    return;
  }
  const int beg = off[dst], end = off[dst + 1];
  float4 acc = make_float4(0.f, 0.f, 0.f, 0.f);
  int deg = 0;
  for (int base = beg; base < end; base += 64) {
    const int n = min(64, end - base);
    int sv = 0;
    float tv = 0.f;
    int live = 0;
    if (lane < n) {
      sv = ssrc[base + lane];
      if (CM) {
        const float2 mt = tm[sv];
        live = (mt.x != 0.f);
        tv = mt.y;
      }
    }
    if (CM)
      deg += (int)__popcll(__ballot(live));
    else
      deg += n;
    int j = half;
    for (; j + 6 < n; j += 8) {  // 4 edges per half in flight
      const int s0 = __shfl(sv, j);
      const int s1 = __shfl(sv, j + 2);
      const int s2 = __shfl(sv, j + 4);
      const int s3 = __shfl(sv, j + 6);
      const float4 v0 = *(const float4*)(x + (size_t)s0 * DD + l * 4);
      const float4 v1 = *(const float4*)(x + (size_t)s1 * DD + l * 4);
      const float4 v2 = *(const float4*)(x + (size_t)s2 * DD + l * 4);
      const float4 v3 = *(const float4*)(x + (size_t)s3 * DD + l * 4);
      if (CM) {
        const float t0 = __shfl(tv, j), t1 = __shfl(tv, j + 2);
        const float t2 = __shfl(tv, j + 4), t3 = __shfl(tv, j + 6);
        acc.x += v0.x * t0 + v1.x * t1 + v2.x * t2 + v3.x * t3;
        acc.y += v0.y * t0 + v1.y * t1 + v2.y * t2 + v3.y * t3;
        acc.z += v0.z * t0 + v1.z * t1 + v2.z * t2 + v3.z * t3;
        acc.w += v0.w * t0 + v1.w * t1 + v2.w * t2 + v3.w * t3;
      } else {
        acc.x += v0.x + v1.x + v2.x + v3.x;
        acc.y += v0.y + v1.y + v2.y + v3.y;
        acc.z += v0.z + v1.z + v2.z + v3.z;
        acc.w += v0.w + v1.w + v2.w + v3.w;
      }
    }
    for (; j < n; j += 2) {
      const int s = __shfl(sv, j);
      const float4 v = *(const float4*)(x + (size_t)s * DD + l * 4);
      if (CM) {
        const float t = __shfl(tv, j);
        acc.x += v.x * t;
        acc.y += v.y * t;
        acc.z += v.z * t;
        acc.w += v.w * t;
      } else {
        acc.x += v.x;
        acc.y += v.y;
        acc.z += v.z;
        acc.w += v.w;
      }
    }
  }
  acc.x += __shfl(acc.x, lane ^ 32);
  acc.y += __shfl(acc.y, lane ^ 32);
  acc.z += __shfl(acc.z, lane ^ 32);
  acc.w += __shfl(acc.w, lane ^ 32);
  const float inv = 1.f / (float)max(deg, 1);
  if (lane < 32) {
    float4 m;
    m.x = acc.x * inv;
    m.y = acc.y * inv;
    m.z = acc.z * inv;
    m.w = acc.w * inv;
    *(float4*)(mean + (size_t)dst * DD + l * 4) = m;
  }
}

// ---------------- MFMA bf16x3 GEMM + score epilogue ----------------
// h = relu([mean | t.*x] @ W + bl); Ax staging rows scaled by tprev (SCALE).
// B: fragment-ordered global loads (no LDS). A: LDS fragment order.

#define GBM 64

template <int SCALE>
__global__ __launch_bounds__(256) void gemm_kernel_t(
    const float* __restrict__ Amean, const float* __restrict__ Ax,
    const float2* __restrict__ tmp,
    const unsigned short* __restrict__ Whi, const unsigned short* __restrict__ Wlo,
    const float* __restrict__ bias, const float* __restrict__ pw,
    float* __restrict__ outp, float* __restrict__ sraw) {
  __shared__ short Ah[2048];  // [m][lane][8]
  __shared__ short Al[2048];
  __shared__ float s_sp[4][GBM];
  const int tid = threadIdx.x;
  const int wv = tid >> 6;
  const int lane = tid & 63;
  const int q = lane >> 4;
  const int li = lane & 15;
  const int row0 = blockIdx.x * GBM;

  int sdst[2];
#pragma unroll
  for (int i = 0; i < 2; ++i) {
    const int id = tid + i * 256;
    const int r = id >> 3;
    const int kb = (id & 7) << 2;
    sdst[i] = ((r >> 4) * 64 + (kb >> 3) * 16 + (r & 15)) * 8 + (kb & 7);
  }

  f32x4 acc[4][2];
#pragma unroll
  for (int m = 0; m < 4; ++m)
#pragma unroll
    for (int n = 0; n < 2; ++n) acc[m][n] = (f32x4){0.f, 0.f, 0.f, 0.f};

  float4 pa[2];
  short8 pbh[2], pbl[2];

#define LOADA(KC)                                                                    \
  {                                                                                  \
    const float* Asrc = ((KC) < 4) ? Amean : Ax;                                     \
    const int cb = ((KC) & 3) * 32;                                                  \
    _Pragma("unroll") for (int i = 0; i < 2; ++i) {                                  \
      const int id = tid + i * 256;                                                  \
      pa[i] = *(const float4*)(Asrc + (size_t)(row0 + (id >> 3)) * DD + cb + ((id & 7) << 2)); \
      if (SCALE && (KC) >= 4) {                                                      \
        const float tt = tmp[row0 + (id >> 3)].y;                                    \
        pa[i].x *= tt; pa[i].y *= tt; pa[i].z *= tt; pa[i].w *= tt;                   \
      }                                                                              \
    }                                                                                \
  }
#define LOADB(KC)                                                                    \
  {                                                                                  \
    _Pragma("unroll") for (int n = 0; n < 2; ++n) {                                  \
      const int ga = (((KC)*8 + wv * 2 + n) * 64 + lane) * 8;                        \
      pbh[n] = *(const short8*)(Whi + ga);                                           \
      pbl[n] = *(const short8*)(Wlo + ga);                                           \
    }                                                                                \
  }

  LOADA(0) LOADB(0)

#pragma unroll
  for (int kc = 0; kc < 8; ++kc) {
#pragma unroll
    for (int i = 0; i < 2; ++i) {
      ushort4 hv, lv;
      hv.x = f2b(pa[i].x); lv.x = f2b(pa[i].x - b2f(hv.x));
      hv.y = f2b(pa[i].y); lv.y = f2b(pa[i].y - b2f(hv.y));
      hv.z = f2b(pa[i].z); lv.z = f2b(pa[i].z - b2f(hv.z));
      hv.w = f2b(pa[i].w); lv.w = f2b(pa[i].w - b2f(hv.w));
      *(ushort4*)(Ah + sdst[i]) = hv;
      *(ushort4*)(Al + sdst[i]) = lv;
    }
    short8 bh[2], bl[2];
    bh[0] = pbh[0]; bh[1] = pbh[1];
    bl[0] = pbl[0]; bl[1] = pbl[1];
    __syncthreads();
    short8 ah[4], al[4];
#pragma unroll
    for (int m = 0; m < 4; ++m) {
      ah[m] = *(const short8*)(Ah + (m * 64 + lane) * 8);
      al[m] = *(const short8*)(Al + (m * 64 + lane) * 8);
    }
    if (kc < 7) { LOADA(kc + 1) LOADB(kc + 1) }  // prefetch overlaps MFMA
#pragma unroll
    for (int m = 0; m < 4; ++m)
#pragma unroll
      for (int n = 0; n < 2; ++n) {
        acc[m][n] = __builtin_amdgcn_mfma_f32_16x16x32_bf16(ah[m], bh[n], acc[m][n], 0, 0, 0);
        acc[m][n] = __builtin_amdgcn_mfma_f32_16x16x32_bf16(ah[m], bl[n], acc[m][n], 0, 0, 0);
        acc[m][n] = __builtin_amdgcn_mfma_f32_16x16x32_bf16(al[m], bh[n], acc[m][n], 0, 0, 0);
      }
    __syncthreads();
  }
#undef LOADA
#undef LOADB

  // epilogue: bias+relu, store h (unscaled), fused score partials
  const int c0 = wv * 32 + li;
  const int c1 = wv * 32 + 16 + li;
  const float b0 = bias[c0], b1 = bias[c1];
  const float p0 = pw[c0], p1 = pw[c1];
  float sp[16];
#pragma unroll
  for (int m = 0; m < 4; ++m) {
#pragma unroll
    for (int i = 0; i < 4; ++i) {
      const int r = row0 + m * 16 + q * 4 + i;
      const float v0 = fmaxf(acc[m][0][i] + b0, 0.f);
      const float v1 = fmaxf(acc[m][1][i] + b1, 0.f);
      outp[(size_t)r * DD + c0] = v0;
      outp[(size_t)r * DD + c1] = v1;
      sp[m * 4 + i] = v0 * p0 + v1 * p1;
    }
  }
#pragma unroll
  for (int e = 0; e < 16; ++e) {
    sp[e] += __shfl_xor(sp[e], 1);
    sp[e] += __shfl_xor(sp[e], 2);
    sp[e] += __shfl_xor(sp[e], 4);
    sp[e] += __shfl_xor(sp[e], 8);
  }
  if (li == 0) {
#pragma unroll
    for (int e = 0; e < 16; ++e) s_sp[wv][(e >> 2) * 16 + q * 4 + (e & 3)] = sp[e];
  }
  __syncthreads();
  if (tid < GBM)
    sraw[row0 + tid] = s_sp[0][tid] + s_sp[1][tid] + s_sp[2][tid] + s_sp[3][tid];
}

// ---------------- topk + readout partials (h is read-only now) ----------------
// 512 blocks = 4/graph, 256 threads. Rank-count (split across 256 thr), write
// tmN = {sel, tanh}, float4 readout partials over SELECTED rows only.

__global__ __launch_bounds__(256) void pool_kernel(const float* __restrict__ h,
                                                   const float* __restrict__ sraw,
                                                   const float* __restrict__ pw,
                                                   const float2* __restrict__ tmP,
                                                   float2* __restrict__ tmN,
                                                   float* __restrict__ zp,
                                                   const int kk) {
  __shared__ float s_sc[NPER];
  __shared__ float s_t[128];
  __shared__ unsigned char s_sel[128];
  __shared__ int s_rk[256];
  __shared__ float4 red4[512];
  __shared__ float s_norm;
  const int b = blockIdx.x;
  const int g = b >> 2;
  const int q = b & 3;
  const int tid = threadIdx.x;
  const int lane = tid & 63;

  if (tid < 64) {
    const float v0 = pw[lane], v1 = pw[lane + 64];
    float p = v0 * v0 + v1 * v1;
#pragma unroll
    for (int o = 32; o > 0; o >>= 1) p += __shfl_down(p, o);
    if (lane == 0) s_norm = 1.f / (sqrtf(p) + 1e-16f);
  }
  __syncthreads();
  const float inv_norm = s_norm;
#pragma unroll
  for (int i = 0; i < 2; ++i) {
    const int n = tid + i * 256;
    const int node = g * NPER + n;
    s_sc[n] = (tmP[node].x != 0.f) ? sraw[node] * inv_norm : -INFINITY;
  }
  __syncthreads();

  // rank-count split: thread pair (tid&127, tid>>7) scans half the scores
  {
    const int n = q * 128 + (tid & 127);
    const int jb = (tid >> 7) * 256;
    const float s = s_sc[n];
    int rank = 0;
    for (int j = jb; j < jb + 256; ++j) {
      const float sj = s_sc[j];
      rank += (sj > s || (sj == s && j < n)) ? 1 : 0;
    }
    s_rk[tid] = rank;
  }
  __syncthreads();
  if (tid < 128) {
    const int n = q * 128 + tid;
    const int rank = s_rk[tid] + s_rk[tid + 128];
    const int sel = (rank < kk) ? 1 : 0;
    const float s = s_sc[n];
    const float t = sel ? tanhf(s) : 0.f;
    tmN[g * NPER + n] = make_float2(sel ? 1.f : 0.f, t);
    s_sel[tid] = (unsigned char)sel;
    s_t[tid] = t;
  }
  __syncthreads();

  // float4 readout partials, selected rows only (h untouched)
  const int c = tid & 31;   // float4 column group
  const int r = tid >> 5;   // 0..7 row group
  float4 pmax = make_float4(-INFINITY, -INFINITY, -INFINITY, -INFINITY);
  float4 psum = make_float4(0.f, 0.f, 0.f, 0.f);
  const size_t nbase = (size_t)g * NPER + q * 128;
  const float4* h4 = (const float4*)h;
  for (int i = 0; i < 16; ++i) {
    const int nl = r + 8 * i;
    if (s_sel[nl]) {
      float4 v = h4[(nbase + nl) * 32 + c];
      const float t = s_t[nl];
      v.x *= t; v.y *= t; v.z *= t; v.w *= t;
      pmax.x = fmaxf(pmax.x, v.x);
      pmax.y = fmaxf(pmax.y, v.y);
      pmax.z = fmaxf(pmax.z, v.z);
      pmax.w = fmaxf(pmax.w, v.w);
      psum.x += v.x; psum.y += v.y; psum.z += v.z; psum.w += v.w;
    }
  }
  red4[r * 32 + c] = pmax;
  red4[256 + r * 32 + c] = psum;
  __syncthreads();
  if (tid < 32) {
    float4 m = red4[tid];
    float4 sm = red4[256 + tid];
#pragma unroll
    for (int rr = 1; rr < 8; ++rr) {
      const float4 a = red4[rr * 32 + tid];
      const float4 s2 = red4[256 + rr * 32 + tid];
      m.x = fmaxf(m.x, a.x); m.y = fmaxf(m.y, a.y);
      m.z = fmaxf(m.z, a.z); m.w = fmaxf(m.w, a.w);
      sm.x += s2.x; sm.y += s2.y; sm.z += s2.z; sm.w += s2.w;
    }
    *(float4*)(zp + (size_t)b * 256 + tid * 4) = m;
    *(float4*)(zp + (size_t)b * 256 + 128 + tid * 4) = sm;
  }
}

// ---------------- MLP head (reduces 4 partials/graph/layer) ----------------

__global__ __launch_bounds__(128) void mlp_kernel(const float* __restrict__ zpart,
                                                  const float* __restrict__ w1,
                                                  const float* __restrict__ b1,
                                                  const float* __restrict__ w2,
                                                  const float* __restrict__ b2,
                                                  const float* __restrict__ w3,
                                                  const float* __restrict__ b3,
                                                  float* __restrict__ out,
                                                  const float ik0, const float ik1,
                                                  const float ik2) {
  __shared__ float z[256];
  __shared__ float h1[128];
  __shared__ float h2[64];
  const int g = blockIdx.x;
  const int t = threadIdx.x;
  const float iks[3] = {ik0, ik1, ik2};
  float zmax = 0.f, zmean = 0.f;
#pragma unroll
  for (int l = 0; l < 3; ++l) {
    const float* zp = zpart + ((size_t)l * 512 + g * 4) * 256;
    zmax += fmaxf(fmaxf(zp[t], zp[256 + t]), fmaxf(zp[512 + t], zp[768 + t]));
    zmean += (zp[128 + t] + zp[384 + t] + zp[640 + t] + zp[896 + t]) * iks[l];
  }
  z[t] = zmax;
  z[128 + t] = zmean;
  __syncthreads();
  float a = b1[t];
  for (int k = 0; k < 256; ++k) a = fmaf(z[k], w1[t * 256 + k], a);
  h1[t] = fmaxf(a, 0.f);
  __syncthreads();
  if (t < 64) {
    float a2 = b2[t];
    for (int k = 0; k < 128; ++k) a2 = fmaf(h1[k], w2[t * 128 + k], a2);
    h2[t] = fmaxf(a2, 0.f);
  }
  __syncthreads();
  if (t == 0) {
    float a3 = b3[0];
    for (int k = 0; k < 64; ++k) a3 = fmaf(h2[k], w3[k], a3);
    out[g] = 1.f / (1.f + expf(-a3));
  }
}

// ---------------- launch ----------------

extern "C" void kernel_launch(void* const* d_in, const int* in_sizes, int n_in,
                              void* d_out, int out_size, void* d_ws, size_t ws_size,
                              hipStream_t stream) {
  (void)in_sizes; (void)n_in; (void)out_size; (void)ws_size;
  const float* x_in = (const float*)d_in[0];
  const int* ei = (const int*)d_in[1];
  const float* wl[3] = {(const float*)d_in[2], (const float*)d_in[6], (const float*)d_in[10]};
  const float* cbl[3] = {(const float*)d_in[3], (const float*)d_in[7], (const float*)d_in[11]};
  const float* wr[3] = {(const float*)d_in[4], (const float*)d_in[8], (const float*)d_in[12]};
  const float* pw[3] = {(const float*)d_in[5], (const float*)d_in[9], (const float*)d_in[13]};
  const float* l1w = (const float*)d_in[14];
  const float* l1b = (const float*)d_in[15];
  const float* l2w = (const float*)d_in[16];
  const float* l2b = (const float*)d_in[17];
  const float* l3w = (const float*)d_in[18];
  const float* l3b = (const float*)d_in[19];
  float* out = (float*)d_out;

  char* w = (char*)d_ws;
  int* counts = (int*)(w + 0 * (1 << 20));  // dead after setup
  int* off = (int*)(w + 1 * (1 << 20));
  int* cursor = (int*)(w + 2 * (1 << 20));  // dead after scatter
  float* sraw = (float*)(w + 2 * (1 << 20));  // reuses cursor (256KB)
  float2* tmA = (float2*)(w + 3 * (1 << 20));              // 512KB
  float2* tmB = (float2*)(w + 3 * (1 << 20) + (1 << 19));  // 512KB
  float* zpart = (float*)(w + 4 * (1 << 20));              // 1.5MB (4..5.5MB)
  unsigned short* Whi = (unsigned short*)(w + 5 * (1 << 20) + (1 << 19));      // 192KB
  unsigned short* Wlo = (unsigned short*)(w + 5 * (1 << 20) + 3 * (1 << 18));  // 192KB
  int* ssrc = (int*)(w + 6 * (1 << 20));               // 2MB
  float* mean = (float*)(w + (size_t)8 * (1 << 20));   // 32MB
  float* hA = (float*)(w + (size_t)40 * (1 << 20));    // 32MB
  float* hB = (float*)(w + (size_t)72 * (1 << 20));    // 32MB (total 104MB)

  init_kernel<<<NND / 256, 256, 0, stream>>>(counts, tmA);
  hist_kernel<<<NED / 256, 256, 0, stream>>>(ei, counts);
  scan_kernel<<<1, 1024, 0, stream>>>(counts, off, cursor);
  scatter_kernel<<<NED / 256, 256, 0, stream>>>(ei, cursor, ssrc);
  prepw_kernel<<<384, 256, 0, stream>>>(wl[0], wr[0], wl[1], wr[1], wl[2], wr[2], Whi, Wlo);

  const int ks[3] = {410, 328, 263};
  const float* xl = x_in;
  float* houts[3] = {hA, hB, hA};
  float2* tprev[3] = {tmA, tmB, tmA};
  float2* tnext[3] = {tmB, tmA, tmB};
  for (int l = 0; l < 3; ++l) {
    float* hout = houts[l];
    if (l == 0) {
      agg_kernel_t<0><<<NND / 4, 256, 0, stream>>>(xl, tprev[l], off, ssrc, mean);
      gemm_kernel_t<0><<<NND / GBM, 256, 0, stream>>>(mean, xl, tprev[l],
                                                      Whi + (size_t)l * 32768,
                                                      Wlo + (size_t)l * 32768, cbl[l], pw[l],
                                                      hout, sraw);
    } else {
      agg_kernel_t<1><<<NND / 4, 256, 0, stream>>>(xl, tprev[l], off, ssrc, mean);
      gemm_kernel_t<1><<<NND / GBM, 256, 0, stream>>>(mean, xl, tprev[l],
                                                      Whi + (size_t)l * 32768,
                                                      Wlo + (size_t)l * 32768, cbl[l], pw[l],
                                                      hout, sraw);
    }
    pool_kernel<<<NGR * 4, 256, 0, stream>>>(hout, sraw, pw[l], tprev[l], tnext[l],
                                             zpart + (size_t)l * 512 * 256, ks[l]);
    xl = hout;
  }
  mlp_kernel<<<NGR, 128, 0, stream>>>(zpart, l1w, l1b, l2w, l2b, l3w, l3b, out,
                                      1.f / 410.f, 1.f / 328.f, 1.f / 263.f);
}

// Round 8
// 406.065 us; speedup vs baseline: 4.1410x; 1.0344x over previous
//
#include <hip/hip_runtime.h>
#include <math.h>

#define NND 65536   // total nodes
#define NPER 512    // nodes per graph
#define NGR 128     // graphs (B)
#define DD 128      // feature dim
#define NED 524288  // edges

typedef __attribute__((ext_vector_type(8))) short short8;
typedef __attribute__((ext_vector_type(4))) float f32x4;

__device__ __forceinline__ unsigned short f2b(float f) {
  unsigned u = __float_as_uint(f);
  return (unsigned short)((u + 0x7FFFu + ((u >> 16) & 1u)) >> 16);
}
__device__ __forceinline__ float b2f(unsigned short h) {
  return __uint_as_float(((unsigned)h) << 16);
}

// ---------------- CSR build ----------------

__global__ __launch_bounds__(256) void init_kernel(int* __restrict__ counts,
                                                   float2* __restrict__ tm) {
  int i = blockIdx.x * 256 + threadIdx.x;
  counts[i] = 0;
  tm[i] = make_float2(1.f, 1.f);  // layer-0: all selected, t=1
}

__global__ __launch_bounds__(256) void hist_kernel(const int* __restrict__ ei,
                                                   int* __restrict__ counts) {
  int e = blockIdx.x * 256 + threadIdx.x;
  atomicAdd(&counts[ei[NED + e]], 1);
}

__global__ __launch_bounds__(1024) void scan_kernel(const int* __restrict__ counts,
                                                    int* __restrict__ off,
                                                    int* __restrict__ cursor) {
  __shared__ int part[1024];
  int t = threadIdx.x;
  int base = t * 64;
  int s = 0;
  const int4* c4 = (const int4*)(counts + base);
  for (int i = 0; i < 16; ++i) {
    int4 v = c4[i];
    s += v.x + v.y + v.z + v.w;
  }
  part[t] = s;
  __syncthreads();
  for (int d = 1; d < 1024; d <<= 1) {
    int v = (t >= d) ? part[t - d] : 0;
    __syncthreads();
    part[t] += v;
    __syncthreads();
  }
  int run = (t == 0) ? 0 : part[t - 1];
  for (int i = 0; i < 64; ++i) {
    off[base + i] = run;
    cursor[base + i] = run;
    run += counts[base + i];
  }
  if (t == 1023) off[NND] = run;
}

__global__ __launch_bounds__(256) void scatter_kernel(const int* __restrict__ ei,
                                                      int* __restrict__ cursor,
                                                      int* __restrict__ ssrc) {
  int e = blockIdx.x * 256 + threadIdx.x;
  int dst = ei[NED + e];
  int pos = atomicAdd(&cursor[dst], 1);
  ssrc[pos] = ei[e];
}

// ---------------- weight prep: bf16 hi/lo in MFMA-FRAGMENT order ----------------

__global__ __launch_bounds__(256) void prepw_kernel(
    const float* __restrict__ wl0, const float* __restrict__ wr0,
    const float* __restrict__ wl1, const float* __restrict__ wr1,
    const float* __restrict__ wl2, const float* __restrict__ wr2,
    unsigned short* __restrict__ Whi, unsigned short* __restrict__ Wlo) {
  const float* wls[3] = {wl0, wl1, wl2};
  const float* wrs[3] = {wr0, wr1, wr2};
  int e = blockIdx.x * 256 + threadIdx.x;  // 3*32768
  int l = e >> 15;
  int o = e & 32767;
  int j = o & 7;
  int lane = (o >> 3) & 63;
  int nt = (o >> 9) & 7;
  int kc = o >> 12;
  int li = lane & 15, q = lane >> 4;
  int n = nt * 16 + li;
  int k = kc * 32 + q * 8 + j;
  const float* src = (k < 128) ? wls[l] : wrs[l];
  float v = src[n * DD + (k & 127)];
  unsigned short hi = f2b(v);
  float lo = v - b2f(hi);
  Whi[e] = hi;
  Wlo[e] = f2b(lo);
}

// ---------------- mean aggregation: 4 dsts/wave, shared prologue ----------------
// Consecutive dsts have contiguous CSR ranges -> ONE coalesced 64-edge window
// load (ssrc + tm gather) serves all 4 dsts; per-dst subrange selected by a
// 64-bit window mask. Output written as bf16 hi/lo pair (mhi/mlo) so gemm's
// mean staging is a pure copy. Dead src rows contribute t=0. XCD swizzle keeps
// a graph's x-slice in one XCD's L2.

template <int CM>
__global__ __launch_bounds__(256) void agg_kernel_t(const float* __restrict__ x,
                                                    const float2* __restrict__ tm,
                                                    const int* __restrict__ off,
                                                    const int* __restrict__ ssrc,
                                                    unsigned short* __restrict__ mhi,
                                                    unsigned short* __restrict__ mlo) {
  const int wave = threadIdx.x >> 6;
  const int lane = threadIdx.x & 63;
  const int half = lane >> 5;
  const int l = lane & 31;
  // 4096 blocks = 8 xcd * 16 graphs * 32 slots; 16 dsts/block, 4/wave
  const int bid = blockIdx.x;
  const int xcd = bid & 7;
  const int slot = bid >> 3;                 // 0..511
  const int graph = xcd * 16 + (slot >> 5);  // 0..127
  const int within = slot & 31;              // 0..31
  const int d0 = graph * NPER + within * 16 + wave * 4;

  // prologue: off[d0..d0+4] + per-dst liveness, one coalesced load each
  int offv = 0;
  if (lane < 5) offv = off[d0 + lane];
  float deadv = 1.f;
  if (CM && lane < 4) deadv = tm[d0 + lane].x;
  const int b0 = __shfl(offv, 0);
  const int b1 = __shfl(offv, 1);
  const int b2 = __shfl(offv, 2);
  const int b3 = __shfl(offv, 3);
  const int e3 = __shfl(offv, 4);
  float dd[4];
  if (CM) {
    dd[0] = __shfl(deadv, 0);
    dd[1] = __shfl(deadv, 1);
    dd[2] = __shfl(deadv, 2);
    dd[3] = __shfl(deadv, 3);
  }
  const int begs[4] = {b0, b1, b2, b3};
  const int ends[4] = {b1, b2, b3, e3};

  float4 acc[4];
  int deg[4];
#pragma unroll
  for (int d = 0; d < 4; ++d) {
    acc[d] = make_float4(0.f, 0.f, 0.f, 0.f);
    deg[d] = 0;
  }

  for (int base = b0; base < e3; base += 64) {
    const int nwin = min(64, e3 - base);
    int sv = 0;
    float tv = 0.f;
    int live = 0;
    if (lane < nwin) {
      sv = ssrc[base + lane];
      if (CM) {
        const float2 mt = tm[sv];
        live = (mt.x != 0.f);
        tv = mt.y;
      }
    }
    unsigned long long bl;
    if (CM)
      bl = __ballot(live);
    else
      bl = (nwin == 64) ? ~0ull : ((1ull << nwin) - 1);

#pragma unroll
    for (int d = 0; d < 4; ++d) {
      if (CM && dd[d] == 0.f) continue;
      const int lo = max(begs[d], base);
      const int hi = min(ends[d], base + 64);
      if (lo >= hi) continue;
      const int j0 = lo - base;
      const int j1 = hi - base;
      const unsigned long long wm =
          (((j1 == 64) ? ~0ull : ((1ull << j1) - 1)) & ~((1ull << j0) - 1));
      deg[d] += (int)__popcll(bl & wm);
      int j = j0 + half;
      for (; j + 6 < j1; j += 8) {  // 4 edges per half in flight
        const int s0 = __shfl(sv, j);
        const int s1 = __shfl(sv, j + 2);
        const int s2 = __shfl(sv, j + 4);
        const int s3 = __shfl(sv, j + 6);
        const float4 v0 = *(const float4*)(x + (size_t)s0 * DD + l * 4);
        const float4 v1 = *(const float4*)(x + (size_t)s1 * DD + l * 4);
        const float4 v2 = *(const float4*)(x + (size_t)s2 * DD + l * 4);
        const float4 v3 = *(const float4*)(x + (size_t)s3 * DD + l * 4);
        if (CM) {
          const float t0 = __shfl(tv, j), t1 = __shfl(tv, j + 2);
          const float t2 = __shfl(tv, j + 4), t3 = __shfl(tv, j + 6);
          acc[d].x += v0.x * t0 + v1.x * t1 + v2.x * t2 + v3.x * t3;
          acc[d].y += v0.y * t0 + v1.y * t1 + v2.y * t2 + v3.y * t3;
          acc[d].z += v0.z * t0 + v1.z * t1 + v2.z * t2 + v3.z * t3;
          acc[d].w += v0.w * t0 + v1.w * t1 + v2.w * t2 + v3.w * t3;
        } else {
          acc[d].x += v0.x + v1.x + v2.x + v3.x;
          acc[d].y += v0.y + v1.y + v2.y + v3.y;
          acc[d].z += v0.z + v1.z + v2.z + v3.z;
          acc[d].w += v0.w + v1.w + v2.w + v3.w;
        }
      }
      for (; j < j1; j += 2) {
        const int s = __shfl(sv, j);
        const float4 v = *(const float4*)(x + (size_t)s * DD + l * 4);
        if (CM) {
          const float t = __shfl(tv, j);
          acc[d].x += v.x * t;
          acc[d].y += v.y * t;
          acc[d].z += v.z * t;
          acc[d].w += v.w * t;
        } else {
          acc[d].x += v.x;
          acc[d].y += v.y;
          acc[d].z += v.z;
          acc[d].w += v.w;
        }
      }
    }
  }

#pragma unroll
  for (int d = 0; d < 4; ++d) {
    float4 a = acc[d];
    a.x += __shfl(a.x, lane ^ 32);
    a.y += __shfl(a.y, lane ^ 32);
    a.z += __shfl(a.z, lane ^ 32);
    a.w += __shfl(a.w, lane ^ 32);
    if (lane < 32) {
      const float inv = 1.f / (float)max(deg[d], 1);
      float4 m;
      m.x = a.x * inv;
      m.y = a.y * inv;
      m.z = a.z * inv;
      m.w = a.w * inv;
      ushort4 hv, lv;
      hv.x = f2b(m.x); lv.x = f2b(m.x - b2f(hv.x));
      hv.y = f2b(m.y); lv.y = f2b(m.y - b2f(hv.y));
      hv.z = f2b(m.z); lv.z = f2b(m.z - b2f(hv.z));
      hv.w = f2b(m.w); lv.w = f2b(m.w - b2f(hv.w));
      const size_t ad = (size_t)(d0 + d) * DD + l * 4;
      *(ushort4*)(mhi + ad) = hv;
      *(ushort4*)(mlo + ad) = lv;
    }
  }
}

// ---------------- MFMA bf16x3 GEMM + score epilogue ----------------
// h = relu([mean | t.*x] @ W + bl). Mean arrives PRE-SPLIT (mhi/mlo from agg)
// -> staging is a pure ushort4 copy, no cvt VALU. Ax (fp32) path keeps the
// hi/lo split + t-scale. B: fragment-ordered global loads (no LDS).

#define GBM 64

template <int SCALE>
__global__ __launch_bounds__(256) void gemm_kernel_t(
    const unsigned short* __restrict__ Amh, const unsigned short* __restrict__ Aml,
    const float* __restrict__ Ax, const float2* __restrict__ tmp,
    const unsigned short* __restrict__ Whi, const unsigned short* __restrict__ Wlo,
    const float* __restrict__ bias, const float* __restrict__ pw,
    float* __restrict__ outp, float* __restrict__ sraw) {
  __shared__ short Ah[2048];  // [m][lane][8]
  __shared__ short Al[2048];
  __shared__ float s_sp[4][GBM];
  const int tid = threadIdx.x;
  const int wv = tid >> 6;
  const int lane = tid & 63;
  const int q = lane >> 4;
  const int li = lane & 15;
  const int row0 = blockIdx.x * GBM;

  int sdst[2];
#pragma unroll
  for (int i = 0; i < 2; ++i) {
    const int id = tid + i * 256;
    const int r = id >> 3;
    const int kb = (id & 7) << 2;
    sdst[i] = ((r >> 4) * 64 + (kb >> 3) * 16 + (r & 15)) * 8 + (kb & 7);
  }

  f32x4 acc[4][2];
#pragma unroll
  for (int m = 0; m < 4; ++m)
#pragma unroll
    for (int n = 0; n < 2; ++n) acc[m][n] = (f32x4){0.f, 0.f, 0.f, 0.f};

  float4 pa[2];
  ushort4 pmh[2], pml[2];
  short8 pbh[2], pbl[2];

#define LOADA(KC)                                                                      \
  {                                                                                    \
    if ((KC) < 4) {                                                                    \
      const int cb = (KC)*32;                                                          \
      _Pragma("unroll") for (int i = 0; i < 2; ++i) {                                  \
        const int id = tid + i * 256;                                                  \
        const size_t ga = (size_t)(row0 + (id >> 3)) * DD + cb + ((id & 7) << 2);      \
        pmh[i] = *(const ushort4*)(Amh + ga);                                          \
        pml[i] = *(const ushort4*)(Aml + ga);                                          \
      }                                                                                \
    } else {                                                                           \
      const int cb = ((KC)&3) * 32;                                                    \
      _Pragma("unroll") for (int i = 0; i < 2; ++i) {                                  \
        const int id = tid + i * 256;                                                  \
        pa[i] = *(const float4*)(Ax + (size_t)(row0 + (id >> 3)) * DD + cb + ((id & 7) << 2)); \
        if (SCALE) {                                                                   \
          const float tt = tmp[row0 + (id >> 3)].y;                                    \
          pa[i].x *= tt; pa[i].y *= tt; pa[i].z *= tt; pa[i].w *= tt;                  \
        }                                                                              \
      }                                                                                \
    }                                                                                  \
  }
#define LOADB(KC)                                                                      \
  {                                                                                    \
    _Pragma("unroll") for (int n = 0; n < 2; ++n) {                                    \
      const int ga = (((KC)*8 + wv * 2 + n) * 64 + lane) * 8;                          \
      pbh[n] = *(const short8*)(Whi + ga);                                             \
      pbl[n] = *(const short8*)(Wlo + ga);                                             \
    }                                                                                  \
  }

  LOADA(0) LOADB(0)

#pragma unroll
  for (int kc = 0; kc < 8; ++kc) {
    if (kc < 4) {
#pragma unroll
      for (int i = 0; i < 2; ++i) {
        *(ushort4*)(Ah + sdst[i]) = pmh[i];
        *(ushort4*)(Al + sdst[i]) = pml[i];
      }
    } else {
#pragma unroll
      for (int i = 0; i < 2; ++i) {
        ushort4 hv, lv;
        hv.x = f2b(pa[i].x); lv.x = f2b(pa[i].x - b2f(hv.x));
        hv.y = f2b(pa[i].y); lv.y = f2b(pa[i].y - b2f(hv.y));
        hv.z = f2b(pa[i].z); lv.z = f2b(pa[i].z - b2f(hv.z));
        hv.w = f2b(pa[i].w); lv.w = f2b(pa[i].w - b2f(hv.w));
        *(ushort4*)(Ah + sdst[i]) = hv;
        *(ushort4*)(Al + sdst[i]) = lv;
      }
    }
    short8 bh[2], bl[2];
    bh[0] = pbh[0]; bh[1] = pbh[1];
    bl[0] = pbl[0]; bl[1] = pbl[1];
    __syncthreads();
    short8 ah[4], al[4];
#pragma unroll
    for (int m = 0; m < 4; ++m) {
      ah[m] = *(const short8*)(Ah + (m * 64 + lane) * 8);
      al[m] = *(const short8*)(Al + (m * 64 + lane) * 8);
    }
    switch (kc) {  // prefetch overlaps MFMA below
      case 0: LOADA(1) LOADB(1) break;
      case 1: LOADA(2) LOADB(2) break;
      case 2: LOADA(3) LOADB(3) break;
      case 3: LOADA(4) LOADB(4) break;
      case 4: LOADA(5) LOADB(5) break;
      case 5: LOADA(6) LOADB(6) break;
      case 6: LOADA(7) LOADB(7) break;
      default: break;
    }
#pragma unroll
    for (int m = 0; m < 4; ++m)
#pragma unroll
      for (int n = 0; n < 2; ++n) {
        acc[m][n] = __builtin_amdgcn_mfma_f32_16x16x32_bf16(ah[m], bh[n], acc[m][n], 0, 0, 0);
        acc[m][n] = __builtin_amdgcn_mfma_f32_16x16x32_bf16(ah[m], bl[n], acc[m][n], 0, 0, 0);
        acc[m][n] = __builtin_amdgcn_mfma_f32_16x16x32_bf16(al[m], bh[n], acc[m][n], 0, 0, 0);
      }
    __syncthreads();
  }
#undef LOADA
#undef LOADB

  // epilogue: bias+relu, store h (unscaled), fused score partials
  const int c0 = wv * 32 + li;
  const int c1 = wv * 32 + 16 + li;
  const float b0 = bias[c0], b1 = bias[c1];
  const float p0 = pw[c0], p1 = pw[c1];
  float sp[16];
#pragma unroll
  for (int m = 0; m < 4; ++m) {
#pragma unroll
    for (int i = 0; i < 4; ++i) {
      const int r = row0 + m * 16 + q * 4 + i;
      const float v0 = fmaxf(acc[m][0][i] + b0, 0.f);
      const float v1 = fmaxf(acc[m][1][i] + b1, 0.f);
      outp[(size_t)r * DD + c0] = v0;
      outp[(size_t)r * DD + c1] = v1;
      sp[m * 4 + i] = v0 * p0 + v1 * p1;
    }
  }
#pragma unroll
  for (int e = 0; e < 16; ++e) {
    sp[e] += __shfl_xor(sp[e], 1);
    sp[e] += __shfl_xor(sp[e], 2);
    sp[e] += __shfl_xor(sp[e], 4);
    sp[e] += __shfl_xor(sp[e], 8);
  }
  if (li == 0) {
#pragma unroll
    for (int e = 0; e < 16; ++e) s_sp[wv][(e >> 2) * 16 + q * 4 + (e & 3)] = sp[e];
  }
  __syncthreads();
  if (tid < GBM)
    sraw[row0 + tid] = s_sp[0][tid] + s_sp[1][tid] + s_sp[2][tid] + s_sp[3][tid];
}

// ---------------- topk + readout partials (h is read-only) ----------------

__global__ __launch_bounds__(256) void pool_kernel(const float* __restrict__ h,
                                                   const float* __restrict__ sraw,
                                                   const float* __restrict__ pw,
                                                   const float2* __restrict__ tmP,
                                                   float2* __restrict__ tmN,
                                                   float* __restrict__ zp,
                                                   const int kk) {
  __shared__ float s_sc[NPER];
  __shared__ float s_t[128];
  __shared__ unsigned char s_sel[128];
  __shared__ int s_rk[256];
  __shared__ float4 red4[512];
  __shared__ float s_norm;
  const int b = blockIdx.x;
  const int g = b >> 2;
  const int q = b & 3;
  const int tid = threadIdx.x;
  const int lane = tid & 63;

  if (tid < 64) {
    const float v0 = pw[lane], v1 = pw[lane + 64];
    float p = v0 * v0 + v1 * v1;
#pragma unroll
    for (int o = 32; o > 0; o >>= 1) p += __shfl_down(p, o);
    if (lane == 0) s_norm = 1.f / (sqrtf(p) + 1e-16f);
  }
  __syncthreads();
  const float inv_norm = s_norm;
#pragma unroll
  for (int i = 0; i < 2; ++i) {
    const int n = tid + i * 256;
    const int node = g * NPER + n;
    s_sc[n] = (tmP[node].x != 0.f) ? sraw[node] * inv_norm : -INFINITY;
  }
  __syncthreads();

  {
    const int n = q * 128 + (tid & 127);
    const int jb = (tid >> 7) * 256;
    const float s = s_sc[n];
    int rank = 0;
    for (int j = jb; j < jb + 256; ++j) {
      const float sj = s_sc[j];
      rank += (sj > s || (sj == s && j < n)) ? 1 : 0;
    }
    s_rk[tid] = rank;
  }
  __syncthreads();
  if (tid < 128) {
    const int n = q * 128 + tid;
    const int rank = s_rk[tid] + s_rk[tid + 128];
    const int sel = (rank < kk) ? 1 : 0;
    const float s = s_sc[n];
    const float t = sel ? tanhf(s) : 0.f;
    tmN[g * NPER + n] = make_float2(sel ? 1.f : 0.f, t);
    s_sel[tid] = (unsigned char)sel;
    s_t[tid] = t;
  }
  __syncthreads();

  const int c = tid & 31;
  const int r = tid >> 5;
  float4 pmax = make_float4(-INFINITY, -INFINITY, -INFINITY, -INFINITY);
  float4 psum = make_float4(0.f, 0.f, 0.f, 0.f);
  const size_t nbase = (size_t)g * NPER + q * 128;
  const float4* h4 = (const float4*)h;
  for (int i = 0; i < 16; ++i) {
    const int nl = r + 8 * i;
    if (s_sel[nl]) {
      float4 v = h4[(nbase + nl) * 32 + c];
      const float t = s_t[nl];
      v.x *= t; v.y *= t; v.z *= t; v.w *= t;
      pmax.x = fmaxf(pmax.x, v.x);
      pmax.y = fmaxf(pmax.y, v.y);
      pmax.z = fmaxf(pmax.z, v.z);
      pmax.w = fmaxf(pmax.w, v.w);
      psum.x += v.x; psum.y += v.y; psum.z += v.z; psum.w += v.w;
    }
  }
  red4[r * 32 + c] = pmax;
  red4[256 + r * 32 + c] = psum;
  __syncthreads();
  if (tid < 32) {
    float4 m = red4[tid];
    float4 sm = red4[256 + tid];
#pragma unroll
    for (int rr = 1; rr < 8; ++rr) {
      const float4 a = red4[rr * 32 + tid];
      const float4 s2 = red4[256 + rr * 32 + tid];
      m.x = fmaxf(m.x, a.x); m.y = fmaxf(m.y, a.y);
      m.z = fmaxf(m.z, a.z); m.w = fmaxf(m.w, a.w);
      sm.x += s2.x; sm.y += s2.y; sm.z += s2.z; sm.w += s2.w;
    }
    *(float4*)(zp + (size_t)b * 256 + tid * 4) = m;
    *(float4*)(zp + (size_t)b * 256 + 128 + tid * 4) = sm;
  }
}

// ---------------- MLP head (reduces 4 partials/graph/layer) ----------------

__global__ __launch_bounds__(128) void mlp_kernel(const float* __restrict__ zpart,
                                                  const float* __restrict__ w1,
                                                  const float* __restrict__ b1,
                                                  const float* __restrict__ w2,
                                                  const float* __restrict__ b2,
                                                  const float* __restrict__ w3,
                                                  const float* __restrict__ b3,
                                                  float* __restrict__ out,
                                                  const float ik0, const float ik1,
                                                  const float ik2) {
  __shared__ float z[256];
  __shared__ float h1[128];
  __shared__ float h2[64];
  const int g = blockIdx.x;
  const int t = threadIdx.x;
  const float iks[3] = {ik0, ik1, ik2};
  float zmax = 0.f, zmean = 0.f;
#pragma unroll
  for (int l = 0; l < 3; ++l) {
    const float* zp = zpart + ((size_t)l * 512 + g * 4) * 256;
    zmax += fmaxf(fmaxf(zp[t], zp[256 + t]), fmaxf(zp[512 + t], zp[768 + t]));
    zmean += (zp[128 + t] + zp[384 + t] + zp[640 + t] + zp[896 + t]) * iks[l];
  }
  z[t] = zmax;
  z[128 + t] = zmean;
  __syncthreads();
  float a = b1[t];
  for (int k = 0; k < 256; ++k) a = fmaf(z[k], w1[t * 256 + k], a);
  h1[t] = fmaxf(a, 0.f);
  __syncthreads();
  if (t < 64) {
    float a2 = b2[t];
    for (int k = 0; k < 128; ++k) a2 = fmaf(h1[k], w2[t * 128 + k], a2);
    h2[t] = fmaxf(a2, 0.f);
  }
  __syncthreads();
  if (t == 0) {
    float a3 = b3[0];
    for (int k = 0; k < 64; ++k) a3 = fmaf(h2[k], w3[k], a3);
    out[g] = 1.f / (1.f + expf(-a3));
  }
}

// ---------------- launch ----------------

extern "C" void kernel_launch(void* const* d_in, const int* in_sizes, int n_in,
                              void* d_out, int out_size, void* d_ws, size_t ws_size,
                              hipStream_t stream) {
  (void)in_sizes; (void)n_in; (void)out_size; (void)ws_size;
  const float* x_in = (const float*)d_in[0];
  const int* ei = (const int*)d_in[1];
  const float* wl[3] = {(const float*)d_in[2], (const float*)d_in[6], (const float*)d_in[10]};
  const float* cbl[3] = {(const float*)d_in[3], (const float*)d_in[7], (const float*)d_in[11]};
  const float* wr[3] = {(const float*)d_in[4], (const float*)d_in[8], (const float*)d_in[12]};
  const float* pw[3] = {(const float*)d_in[5], (const float*)d_in[9], (const float*)d_in[13]};
  const float* l1w = (const float*)d_in[14];
  const float* l1b = (const float*)d_in[15];
  const float* l2w = (const float*)d_in[16];
  const float* l2b = (const float*)d_in[17];
  const float* l3w = (const float*)d_in[18];
  const float* l3b = (const float*)d_in[19];
  float* out = (float*)d_out;

  char* w = (char*)d_ws;
  int* counts = (int*)(w + 0 * (1 << 20));  // dead after setup
  int* off = (int*)(w + 1 * (1 << 20));
  int* cursor = (int*)(w + 2 * (1 << 20));  // dead after scatter
  float* sraw = (float*)(w + 2 * (1 << 20));  // reuses cursor (256KB)
  float2* tmA = (float2*)(w + 3 * (1 << 20));              // 512KB
  float2* tmB = (float2*)(w + 3 * (1 << 20) + (1 << 19));  // 512KB
  float* zpart = (float*)(w + 4 * (1 << 20));              // 1.5MB (4..5.5MB)
  unsigned short* Whi = (unsigned short*)(w + 5 * (1 << 20) + (1 << 19));      // 192KB
  unsigned short* Wlo = (unsigned short*)(w + 5 * (1 << 20) + 3 * (1 << 18));  // 192KB
  int* ssrc = (int*)(w + 6 * (1 << 20));               // 2MB
  unsigned short* mhi = (unsigned short*)(w + (size_t)8 * (1 << 20));   // 16MB
  unsigned short* mlo = (unsigned short*)(w + (size_t)24 * (1 << 20));  // 16MB
  float* hA = (float*)(w + (size_t)40 * (1 << 20));    // 32MB
  float* hB = (float*)(w + (size_t)72 * (1 << 20));    // 32MB (total 104MB)

  init_kernel<<<NND / 256, 256, 0, stream>>>(counts, tmA);
  hist_kernel<<<NED / 256, 256, 0, stream>>>(ei, counts);
  scan_kernel<<<1, 1024, 0, stream>>>(counts, off, cursor);
  scatter_kernel<<<NED / 256, 256, 0, stream>>>(ei, cursor, ssrc);
  prepw_kernel<<<384, 256, 0, stream>>>(wl[0], wr[0], wl[1], wr[1], wl[2], wr[2], Whi, Wlo);

  const int ks[3] = {410, 328, 263};
  const float* xl = x_in;
  float* houts[3] = {hA, hB, hA};
  float2* tprev[3] = {tmA, tmB, tmA};
  float2* tnext[3] = {tmB, tmA, tmB};
  for (int l = 0; l < 3; ++l) {
    float* hout = houts[l];
    if (l == 0) {
      agg_kernel_t<0><<<4096, 256, 0, stream>>>(xl, tprev[l], off, ssrc, mhi, mlo);
      gemm_kernel_t<0><<<NND / GBM, 256, 0, stream>>>(mhi, mlo, xl, tprev[l],
                                                      Whi + (size_t)l * 32768,
                                                      Wlo + (size_t)l * 32768, cbl[l], pw[l],
                                                      hout, sraw);
    } else {
      agg_kernel_t<1><<<4096, 256, 0, stream>>>(xl, tprev[l], off, ssrc, mhi, mlo);
      gemm_kernel_t<1><<<NND / GBM, 256, 0, stream>>>(mhi, mlo, xl, tprev[l],
                                                      Whi + (size_t)l * 32768,
                                                      Wlo + (size_t)l * 32768, cbl[l], pw[l],
                                                      hout, sraw);
    }
    pool_kernel<<<NGR * 4, 256, 0, stream>>>(hout, sraw, pw[l], tprev[l], tnext[l],
                                             zpart + (size_t)l * 512 * 256, ks[l]);
    xl = hout;
  }
  mlp_kernel<<<NGR, 128, 0, stream>>>(zpart, l1w, l1b, l2w, l2b, l3w, l3b, out,
                                      1.f / 410.f, 1.f / 328.f, 1.f / 263.f);
}